// Round 7
// baseline (651.001 us; speedup 1.0000x reference)
//
#include <hip/hip_runtime.h>
#include <hip/hip_bf16.h>

#define SCALE_F 0.17677669529663688f  // 1/sqrt(32)

typedef __attribute__((ext_vector_type(8)))  short bfrag;   // 8 bf16 = 4 VGPRs
typedef __attribute__((ext_vector_type(16))) float facc;    // 32x32 C/D: 16 fp32
typedef __attribute__((ext_vector_type(2)))  float f32x2;   // packs to v_pk_* on CDNA

extern "C" __device__ float __ocml_native_exp2_f32(float);  // bare v_exp_f32

__device__ __forceinline__ float lo16(unsigned u){ return __uint_as_float(u << 16); }
__device__ __forceinline__ float hi16(unsigned u){ return __uint_as_float(u & 0xffff0000u); }
__device__ __forceinline__ float bu2f(unsigned short u){ return __uint_as_float((unsigned)u << 16); }
__device__ __forceinline__ unsigned short f2bu(float f){
    __hip_bfloat16 h = __float2bfloat16(f);
    return *reinterpret_cast<unsigned short*>(&h);
}
__device__ __forceinline__ void storeC(float* p, float v){ *p = v; }
__device__ __forceinline__ void storeC(__hip_bfloat16* p, float v){ *p = __float2bfloat16(v); }

// ---------------- CSR build (dual-side kernels: blockIdx.y / blockIdx.x selects side) --
__global__ void hist2_k(const int* __restrict__ d1, int* __restrict__ c1, int E1, int N1,
                        const int* __restrict__ d2, int* __restrict__ c2, int E2, int N2){
    const int* d = blockIdx.y ? d2 : d1;
    int* c = blockIdx.y ? c2 : c1;
    int E = blockIdx.y ? E2 : E1;
    int Nd = blockIdx.y ? N2 : N1;
    int e = blockIdx.x*256 + threadIdx.x;
    if (e >= E) return;
    int dd = d[e];
    if ((unsigned)dd < (unsigned)Nd) atomicAdd(&c[dd], 1);
}

__global__ void scan_block2_k(const int* __restrict__ c1, int* __restrict__ i1, int* __restrict__ b1, int N1,
                              const int* __restrict__ c2, int* __restrict__ i2, int* __restrict__ b2, int N2){
    const int* cnt = blockIdx.y ? c2 : c1;
    int* incl = blockIdx.y ? i2 : i1;
    int* bsum = blockIdx.y ? b2 : b1;
    int N = blockIdx.y ? N2 : N1;
    if ((int)blockIdx.x*256 >= N) return;
    __shared__ int sh[256];
    int tid = threadIdx.x;
    int i = blockIdx.x*256 + tid;
    int v = (i < N) ? cnt[i] : 0;
    sh[tid] = v;
    __syncthreads();
    for (int off = 1; off < 256; off <<= 1){
        int t = (tid >= off) ? sh[tid-off] : 0;
        __syncthreads();
        sh[tid] += t;
        __syncthreads();
    }
    if (i < N) incl[i] = sh[tid];
    if (tid == 255) bsum[blockIdx.x] = sh[255];
}

__global__ void scan_top2_k(int* __restrict__ b1, int nb1, int* __restrict__ b2, int nb2){
    int* bsum = blockIdx.x ? b2 : b1;
    int nb = blockIdx.x ? nb2 : nb1;
    __shared__ int sh[512];
    int tid = threadIdx.x;
    int v = (tid < nb) ? bsum[tid] : 0;
    sh[tid] = v;
    __syncthreads();
    for (int off = 1; off < 512; off <<= 1){
        int t = (tid >= off) ? sh[tid-off] : 0;
        __syncthreads();
        sh[tid] += t;
        __syncthreads();
    }
    if (tid < nb) bsum[tid] = sh[tid] - v;  // exclusive
}

__global__ void finalize2_k(const int* __restrict__ i1, const int* __restrict__ c1,
                            const int* __restrict__ b1, int* __restrict__ p1, int N1, int E1,
                            const int* __restrict__ i2, const int* __restrict__ c2,
                            const int* __restrict__ b2, int* __restrict__ p2, int N2, int E2){
    const int* incl = blockIdx.y ? i2 : i1;
    const int* cnt  = blockIdx.y ? c2 : c1;
    const int* boff = blockIdx.y ? b2 : b1;
    int* indptr = blockIdx.y ? p2 : p1;
    int N = blockIdx.y ? N2 : N1;
    int E = blockIdx.y ? E2 : E1;
    int i = blockIdx.x*256 + threadIdx.x;
    if (i > N) return;
    if (i == N){ indptr[N] = E; return; }
    indptr[i] = boff[i >> 8] + incl[i] - cnt[i];
}

__global__ void scatter2_k(const int* __restrict__ s1, const int* __restrict__ d1,
                           const int* __restrict__ p1, int* __restrict__ u1,
                           int* __restrict__ r1, int E1, int N1,
                           const int* __restrict__ s2, const int* __restrict__ d2,
                           const int* __restrict__ p2, int* __restrict__ u2,
                           int* __restrict__ r2, int E2, int N2){
    const int* src = blockIdx.y ? s2 : s1;
    const int* dst = blockIdx.y ? d2 : d1;
    const int* indptr = blockIdx.y ? p2 : p1;
    int* cur = blockIdx.y ? u2 : u1;
    int* csr = blockIdx.y ? r2 : r1;
    int E = blockIdx.y ? E2 : E1;
    int Nd = blockIdx.y ? N2 : N1;
    int e = blockIdx.x*256 + threadIdx.x;
    if (e >= E) return;
    int d = dst[e];
    if ((unsigned)d >= (unsigned)Nd) return;
    int p = indptr[d] + atomicAdd(&cur[d], 1);
    csr[p] = src[e];
}

// ---------------- input projection: weight-stationary, LDS x-broadcast --------------
template<int K>
__device__ __forceinline__ void in_proj_body(const float* __restrict__ x,
                                             const float* __restrict__ W,
                                             const float* __restrict__ b,
                                             unsigned short* __restrict__ h, int N){
    constexpr int KP4 = (K + 3)/4, KP = KP4*4;
    int j = threadIdx.x;
    float wreg[KP];
    #pragma unroll
    for (int k = 0; k < KP; ++k) wreg[k] = (k < K) ? W[k*128 + j] : 0.f;
    float bj = b[j];
    __shared__ float xs[8][KP];
    for (int base = blockIdx.x*8; base < N; base += gridDim.x*8){
        __syncthreads();
        for (int t = threadIdx.x; t < 8*KP; t += 128){
            int r = t / KP, k = t - r*KP;
            int row = base + r;
            xs[r][k] = (row < N && k < K) ? x[(size_t)row*K + k] : 0.f;
        }
        __syncthreads();
        #pragma unroll
        for (int r = 0; r < 8; ++r){
            int row = base + r;
            if (row >= N) break;
            float acc = bj;
            #pragma unroll
            for (int kk = 0; kk < KP4; ++kk){
                float4 xv = *(const float4*)(&xs[r][kk*4]);
                acc += xv.x*wreg[kk*4] + xv.y*wreg[kk*4+1]
                     + xv.z*wreg[kk*4+2] + xv.w*wreg[kk*4+3];
            }
            h[(size_t)row*128 + j] = f2bu(acc);
        }
    }
}

__global__ __launch_bounds__(128) void in_proj2_k(
    const float* __restrict__ xm, const float* __restrict__ Wm,
    const float* __restrict__ bm_, unsigned short* __restrict__ hm, int Nm,
    const float* __restrict__ xg, const float* __restrict__ Wg,
    const float* __restrict__ bg_, unsigned short* __restrict__ hg, int Ng){
    if (blockIdx.y == 0) in_proj_body<20>(xm, Wm, bm_, hm, Nm);
    else                 in_proj_body<50>(xg, Wg, bg_, hg, Ng);
}

// ---------------- unified weight prep: QKV-fused weights (both layers, both sides)
// + 6-way 128x128 transposes, one launch ---------------------------------------------
__global__ __launch_bounds__(128) void wprep_k(
    const float* __restrict__ Wq_m, const float* __restrict__ bq_m,
    const float* __restrict__ Wk_m, const float* __restrict__ bk_m,
    const float* __restrict__ Wv_m, const float* __restrict__ bv_m,
    const float* __restrict__ a_mg, const float* __restrict__ m_mg,
    const float* __restrict__ Wq_g, const float* __restrict__ bq_g,
    const float* __restrict__ Wk_g, const float* __restrict__ bk_g,
    const float* __restrict__ Wv_g, const float* __restrict__ bv_g,
    const float* __restrict__ a_gm, const float* __restrict__ m_gm,
    unsigned short* __restrict__ Wtf, float* __restrict__ bfv,
    const float* __restrict__ Wa_m, const float* __restrict__ Wa_g,
    const float* __restrict__ W_out_m, const float* __restrict__ W_out_g,
    unsigned short* __restrict__ Wta, unsigned short* __restrict__ Wtout){
    int b = blockIdx.x;
    if (b < 1536){
        int u = b / 384, j = b % 384;
        int l = u >> 1;  bool sg = (u & 1);
        const float* Wq = (sg ? Wq_g : Wq_m) + l*16384;
        const float* bq = (sg ? bq_g : bq_m) + l*128;
        const float* Wk = (sg ? Wk_g : Wk_m) + l*16384;
        const float* bk = (sg ? bk_g : bk_m) + l*128;
        const float* Wv = (sg ? Wv_g : Wv_m) + l*16384;
        const float* bv = (sg ? bv_g : bv_m) + l*128;
        const float* ar = (sg ? a_gm : a_mg) + l*4096;
        const float* mr = (sg ? m_gm : m_mg) + l*4096;
        unsigned short* Wt = Wtf + (size_t)u*49152;
        float* bf = bfv + u*384;
        int row = threadIdx.x;
        int part = j >> 7, f = j & 127, hh = f >> 5, ff = f & 31;
        float v;
        if (part == 0) v = Wq[row*128 + f];
        else {
            const float* Wx  = (part == 1) ? Wk : Wv;
            const float* rel = (part == 1) ? ar : mr;
            float s = 0.f;
            #pragma unroll
            for (int d = 0; d < 32; ++d)
                s += Wx[row*128 + hh*32 + d] * rel[hh*1024 + d*32 + ff];
            v = s;
        }
        Wt[(size_t)j*128 + row] = f2bu(v);
        if (row == 0){
            float bb;
            if (part == 0) bb = bq[f];
            else {
                const float* bx  = (part == 1) ? bk : bv;
                const float* rel = (part == 1) ? ar : mr;
                float s = 0.f;
                for (int d = 0; d < 32; ++d)
                    s += bx[hh*32 + d] * rel[hh*1024 + d*32 + ff];
                bb = s;
            }
            bf[j] = bb;
        }
    } else {
        int t = b - 1536;
        int y = t >> 7;
        int idx = (t & 127)*128 + threadIdx.x;
        const float* S = (y==0)?Wa_m:(y==1)?Wa_g:(y==2)?(Wa_m+16384):(y==3)?(Wa_g+16384)
                        :(y==4)?W_out_m:W_out_g;
        unsigned short* D = (y==0)?Wta:(y==1)?(Wta+16384):(y==2)?(Wta+32768):(y==3)?(Wta+49152)
                           :(y==4)?Wtout:(Wtout+16384);
        int n = idx >> 7, k = idx & 127;
        D[idx] = f2bu(S[k*128 + n]);
    }
}

// ---------------- MFMA GEMM, two independent sides in one launch ---------------------
// C/D: col=lane&31, row=(reg&3)+8*(reg>>2)+4*(lane>>5)   [m74/m101 verified]
// R4 structure (measured best): 128-col chunks, 2 accumulators/wave, LDS 52KB,
// 16 MFMAs per barrier pair. R6 proved 64-col/4-blocks-per-CU regresses (-13us:
// fewer MFMAs per barrier outweighs occupancy). R3 proved B-direct-from-L2
// regresses (stride-256B uncoalesced). NEW: register prefetch of next B chunk --
// issue chunk+1 global loads before the current chunk's MFMA consumes LDS, so the
// ~500cy load latency hides under 16 MFMAs + epilogue instead of sitting between
// barriers. Chunk loop fully unrolled -> breg rotation is static (no scratch).
// MODE 0: plain store to C (ldc). MODE 1: split-QKV store (chunk 0 -> q[row*128],
// chunks 1,2 -> kv[row*256]; branch is chunk-uniform, constant-folds).
// MODE 2: skip-blend + ELU RMW on H.
template<typename CT, int MODE, int NCHUNK>
__global__ __launch_bounds__(256) void mfma_gemm2(
    const unsigned short* __restrict__ A0, const unsigned short* __restrict__ Wt0,
    const float* __restrict__ bias0, CT* __restrict__ C0, unsigned short* __restrict__ H0,
    int N0, const float* __restrict__ skip0,
    const unsigned short* __restrict__ A1, const unsigned short* __restrict__ Wt1,
    const float* __restrict__ bias1, CT* __restrict__ C1, unsigned short* __restrict__ H1,
    int N1, const float* __restrict__ skip1,
    int ldc, int nblk0){
    bool s0 = ((int)blockIdx.x < nblk0);
    const unsigned short* A  = s0 ? A0 : A1;
    const unsigned short* Wt = s0 ? Wt0 : Wt1;
    const float* bias = s0 ? bias0 : bias1;
    CT* C = s0 ? C0 : C1;
    unsigned short* H = s0 ? H0 : H1;
    int N = s0 ? N0 : N1;
    const float* skip = s0 ? skip0 : skip1;
    int bx = s0 ? blockIdx.x : (blockIdx.x - nblk0);

    __shared__ unsigned short As[64][136];
    __shared__ unsigned short Bs[128][136];
    int tid = threadIdx.x;
    int rb = bx*64;
    #pragma unroll
    for (int ph = 0; ph < 4; ++ph){
        int c = ph*256 + tid;
        int r = c >> 4, off = (c & 15)*8;
        uint4 v = make_uint4(0,0,0,0);
        if (rb + r < N) v = ((const uint4*)(A + (size_t)(rb + r)*128))[c & 15];
        *(uint4*)(&As[r][off]) = v;
    }
    int w = tid >> 6, lane = tid & 63;
    int wr = (w >> 1)*32, wc = (w & 1)*64;
    int m = lane & 31, quad = lane >> 5;
    const unsigned short* ap  = &As[wr + m][quad*8];
    const unsigned short* bp0 = &Bs[wc + m][quad*8];
    const unsigned short* bp1 = &Bs[wc + 32 + m][quad*8];
    float bm = 0.f;
    if (MODE == 2) bm = 1.f/(1.f + __expf(-skip[0]));

    // register-staged B chunk (prefetch pipeline)
    int brow = tid >> 4, bidx = tid & 15, boff = bidx*8;
    uint4 breg[8];
    #pragma unroll
    for (int ph = 0; ph < 8; ++ph)
        breg[ph] = ((const uint4*)(Wt + (size_t)(ph*16 + brow)*128))[bidx];

    #pragma unroll
    for (int chunk = 0; chunk < NCHUNK; ++chunk){
        if (chunk > 0) __syncthreads();   // all waves done reading Bs of prev chunk
        #pragma unroll
        for (int ph = 0; ph < 8; ++ph)
            *(uint4*)(&Bs[ph*16 + brow][boff]) = breg[ph];
        // prefetch next chunk's B into registers (hides under MFMA + epilogue)
        if (chunk + 1 < NCHUNK){
            #pragma unroll
            for (int ph = 0; ph < 8; ++ph)
                breg[ph] = ((const uint4*)(Wt + (size_t)((chunk+1)*128 + ph*16 + brow)*128))[bidx];
        }
        __syncthreads();                   // covers As on chunk 0 as well
        facc acc0, acc1;
        #pragma unroll
        for (int i = 0; i < 16; ++i){ acc0[i] = 0.f; acc1[i] = 0.f; }
        #pragma unroll
        for (int kc = 0; kc < 8; ++kc){
            bfrag a  = *(const bfrag*)(ap  + kc*16);
            bfrag b0 = *(const bfrag*)(bp0 + kc*16);
            bfrag b1 = *(const bfrag*)(bp1 + kc*16);
            acc0 = __builtin_amdgcn_mfma_f32_32x32x16_bf16(a, b0, acc0, 0, 0, 0);
            acc1 = __builtin_amdgcn_mfma_f32_32x32x16_bf16(a, b1, acc1, 0, 0, 0);
        }
        int cb = chunk*128;
        int col0 = cb + wc + m, col1 = col0 + 32;
        float bias0v = bias[col0], bias1v = bias[col1];
        #pragma unroll
        for (int r = 0; r < 16; ++r){
            int lrow = wr + 4*quad + (r & 3) + 8*(r >> 2);
            int grow = rb + lrow;
            if (grow >= N) continue;
            float o0 = acc0[r] + bias0v;
            float o1 = acc1[r] + bias1v;
            if (MODE == 0){
                storeC(&C[(size_t)grow*ldc + col0], o0);
                storeC(&C[(size_t)grow*ldc + col1], o1);
            } else if (MODE == 1){
                unsigned short* qp = (unsigned short*)C;
                if (col0 < 128){
                    qp[(size_t)grow*128 + col0] = f2bu(o0);
                    qp[(size_t)grow*128 + col1] = f2bu(o1);
                } else {
                    H[(size_t)grow*256 + (col0 - 128)] = f2bu(o0);
                    H[(size_t)grow*256 + (col1 - 128)] = f2bu(o1);
                }
            } else {
                size_t i0 = (size_t)grow*128 + col0, i1 = (size_t)grow*128 + col1;
                float v0 = bm*o0 + (1.f - bm)*bu2f(H[i0]);
                float v1 = bm*o1 + (1.f - bm)*bu2f(H[i1]);
                v0 = (v0 > 0.f) ? v0 : expm1f(v0);
                v1 = (v1 > 0.f) ? v1 : expm1f(v1);
                H[i0] = f2bu(v0);
                H[i1] = f2bu(v1);
            }
        }
    }
}

// ---------------- edge attention v7: split q/kv layout ------------------------------
// q row = 128 bf16 (256B); kv row = 256 bf16 (512B contiguous: kt [0:256)B, vt [256:512)B).
// Measured 77.0us (R6) vs 79.0 (R4 768B-stride layout) -- keep. FETCH unchanged
// (224.8MB): the win was address-arithmetic simplicity, not traffic.
// Lane (slot=lane>>4, j=lane&15): 8 dims (uint4 j) of slot's edge; head = j>>2.
// 2-deep pipeline (csr 2 ahead, K/V 1 ahead) -- measured optimum (R2: 3-deep regressed).
__global__ __launch_bounds__(256) void edge_attn7_k(
    const int* __restrict__ ipA, const int* __restrict__ csrA,
    const unsigned short* __restrict__ qdA, const unsigned short* __restrict__ kvA,
    const float* __restrict__ pA, unsigned* __restrict__ aggA, int NdA,
    const int* __restrict__ ipB, const int* __restrict__ csrB,
    const unsigned short* __restrict__ qdB, const unsigned short* __restrict__ kvB,
    const float* __restrict__ pB, unsigned* __restrict__ aggB, int NdB,
    int nblkA){
    bool sA = ((int)blockIdx.x < nblkA);
    const int* ip  = sA ? ipA : ipB;
    const int* csr = sA ? csrA : csrB;
    const uint4* qd = (const uint4*)(sA ? qdA : qdB);
    const char* kvc = (const char*)(sA ? kvA : kvB);
    const float* p = sA ? pA : pB;
    unsigned* agg = sA ? aggA : aggB;
    int Nd = sA ? NdA : NdB;
    int bx = sA ? blockIdx.x : (blockIdx.x - nblkA);
    int wid  = (bx << 2) | (threadIdx.x >> 6);
    int lane = threadIdx.x & 63;
    if (wid >= Nd) return;
    int slot = lane >> 4, j = lane & 15;
    // fold log2(e) into the per-head scale: exp(x) == exp2(x*log2e) -> bare v_exp_f32
    float phL = p[j >> 2] * (SCALE_F * 1.4426950408889634f);
    uint4 qv = qd[(size_t)wid*16 + j];
    f32x2 q2[4];
    q2[0] = (f32x2){lo16(qv.x), hi16(qv.x)};
    q2[1] = (f32x2){lo16(qv.y), hi16(qv.y)};
    q2[2] = (f32x2){lo16(qv.z), hi16(qv.z)};
    q2[3] = (f32x2){lo16(qv.w), hi16(qv.w)};
    int beg = ip[wid], end = ip[wid + 1];
    float den = 0.f;
    f32x2 acc2[4] = {};
    int loff = j*16;
    int i0 = beg + slot;
    if (i0 < end){
        int s0c = csr[i0];
        int i1 = i0 + 4;
        bool m1 = (i1 < end);
        int s1 = m1 ? csr[i1] : 0;          // csr one ahead, ready before loop
        const char* b0 = kvc + (size_t)s0c*512 + loff;
        uint4 kv = *(const uint4*)(b0);
        uint4 vv = *(const uint4*)(b0 + 256);
        while (true){
            // csr TWO ahead; K/V ONE ahead with address already in registers
            int i2 = i1 + 4;
            bool m2 = (i2 < end);
            int s2 = m2 ? csr[i2] : 0;
            uint4 kv2, vv2;
            if (m1){
                const char* b1 = kvc + (size_t)s1*512 + loff;
                kv2 = *(const uint4*)(b1);
                vv2 = *(const uint4*)(b1 + 256);
            }
            f32x2 pp = q2[0] * (f32x2){lo16(kv.x), hi16(kv.x)};
            pp += q2[1] * (f32x2){lo16(kv.y), hi16(kv.y)};
            pp += q2[2] * (f32x2){lo16(kv.z), hi16(kv.z)};
            pp += q2[3] * (f32x2){lo16(kv.w), hi16(kv.w)};
            float part = pp.x + pp.y;
            part += __shfl_xor(part, 1);   // reduce within 4-lane head group
            part += __shfl_xor(part, 2);
            float e = __ocml_native_exp2_f32(part * phL);
            den += e;
            acc2[0] += (f32x2){lo16(vv.x), hi16(vv.x)} * e;
            acc2[1] += (f32x2){lo16(vv.y), hi16(vv.y)} * e;
            acc2[2] += (f32x2){lo16(vv.z), hi16(vv.z)} * e;
            acc2[3] += (f32x2){lo16(vv.w), hi16(vv.w)} * e;
            if (!m1) break;
            kv = kv2; vv = vv2;
            i1 = i2; m1 = m2; s1 = s2;
        }
    }
    // cross-slot reduce (slots hold disjoint edge subsets)
    den += __shfl_xor(den, 16);
    den += __shfl_xor(den, 32);
    #pragma unroll
    for (int k = 0; k < 4; ++k){
        f32x2 t;
        t.x = __shfl_xor(acc2[k].x, 16);
        t.y = __shfl_xor(acc2[k].y, 16);
        acc2[k] += t;
        t.x = __shfl_xor(acc2[k].x, 32);
        t.y = __shfl_xor(acc2[k].y, 32);
        acc2[k] += t;
    }
    float inv = (den > 0.f) ? 1.f/den : 0.f;
    // epilogue: each lane handles dims {8j + 2*slot, 8j + 2*slot + 1} = acc2[slot]
    f32x2 sel = (slot & 2) ? ((slot & 1) ? acc2[3] : acc2[2])
                           : ((slot & 1) ? acc2[1] : acc2[0]);
    float o0 = sel.x*inv, o1 = sel.y*inv;
    o0 = 0.5f*o0*(1.f + erff(o0*0.70710678118654752f));
    o1 = 0.5f*o1*(1.f + erff(o1*0.70710678118654752f));
    agg[(size_t)wid*64 + j*4 + slot] = (unsigned)f2bu(o0) | ((unsigned)f2bu(o1) << 16);
}

// ---------------- host launcher ----------------
extern "C" void kernel_launch(void* const* d_in, const int* in_sizes, int n_in,
                              void* d_out, int out_size, void* d_ws, size_t ws_size,
                              hipStream_t stream){
    typedef const float* FP;
    FP x_m = (FP)d_in[0], x_g = (FP)d_in[1];
    FP W_in_m = (FP)d_in[2], b_in_m = (FP)d_in[3], W_in_g = (FP)d_in[4], b_in_g = (FP)d_in[5];
    FP Wk_m = (FP)d_in[6],  bk_m = (FP)d_in[7],  Wq_m = (FP)d_in[8],  bq_m = (FP)d_in[9];
    FP Wv_m = (FP)d_in[10], bv_m = (FP)d_in[11];
    FP Wk_g = (FP)d_in[12], bk_g = (FP)d_in[13], Wq_g = (FP)d_in[14], bq_g = (FP)d_in[15];
    FP Wv_g = (FP)d_in[16], bv_g = (FP)d_in[17];
    FP a_mg = (FP)d_in[18], m_mg = (FP)d_in[19], p_mg = (FP)d_in[20];
    FP a_gm = (FP)d_in[21], m_gm = (FP)d_in[22], p_gm = (FP)d_in[23];
    FP Wa_m = (FP)d_in[24], ba_m = (FP)d_in[25], Wa_g = (FP)d_in[26], ba_g = (FP)d_in[27];
    FP skip_m = (FP)d_in[28], skip_g = (FP)d_in[29];
    FP W_out_m = (FP)d_in[30], b_out_m = (FP)d_in[31], W_out_g = (FP)d_in[32], b_out_g = (FP)d_in[33];
    const int* e_mg_src = (const int*)d_in[34];
    const int* e_mg_dst = (const int*)d_in[35];
    const int* e_gm_src = (const int*)d_in[36];
    const int* e_gm_dst = (const int*)d_in[37];

    const int Nm = in_sizes[0] / 20;
    const int Ng = in_sizes[1] / 50;
    const int E1 = in_sizes[34];   // m -> g
    const int E2 = in_sizes[36];   // g -> m

    // ---- workspace carve (256B aligned) ----
    char* wp = (char*)d_ws;
    auto alloc = [&](size_t bytes) -> char* {
        char* r = wp; wp += (bytes + 255) & ~(size_t)255; return r;
    };
    unsigned short* h_m   = (unsigned short*)alloc((size_t)Nm*128*2);
    unsigned short* h_g   = (unsigned short*)alloc((size_t)Ng*128*2);
    unsigned short* agg_m = (unsigned short*)alloc((size_t)Nm*128*2);
    unsigned short* agg_g = (unsigned short*)alloc((size_t)Ng*128*2);
    unsigned short* q_m   = (unsigned short*)alloc((size_t)Nm*128*2);
    unsigned short* kv_m  = (unsigned short*)alloc((size_t)Nm*256*2);
    unsigned short* q_g   = (unsigned short*)alloc((size_t)Ng*128*2);
    unsigned short* kv_g  = (unsigned short*)alloc((size_t)Ng*256*2);
    unsigned short* Wtf   = (unsigned short*)alloc((size_t)4*49152*2);  // [l*2+side][384][128]
    float*          bfv   = (float*)alloc((size_t)4*384*4);
    unsigned short* Wta   = (unsigned short*)alloc((size_t)4*16384*2);  // [l*2+side]
    unsigned short* Wtout = (unsigned short*)alloc((size_t)2*16384*2);
    int* indptr_g = (int*)alloc((size_t)(Ng+1)*4);
    int* csr_mg   = (int*)alloc((size_t)E1*4);
    int* indptr_m = (int*)alloc((size_t)(Nm+1)*4);
    int* csr_gm   = (int*)alloc((size_t)E2*4);
    int maxN = Nm > Ng ? Nm : Ng;
    int* cnt  = (int*)alloc((size_t)maxN*4);
    int* cur  = (int*)alloc((size_t)maxN*4);
    int* cnt2 = (int*)alloc((size_t)maxN*4);
    int* cur2 = (int*)alloc((size_t)maxN*4);
    int* incl = (int*)alloc((size_t)maxN*4);
    int* incl2= (int*)alloc((size_t)maxN*4);
    int* bsum = (int*)alloc(512*4);
    int* bsum2= (int*)alloc(512*4);

    size_t used = (size_t)(wp - (char*)d_ws);
    if (used > ws_size){
        hipMemsetAsync(d_out, 0, (size_t)out_size*4, stream);
        return;
    }
    // zero only the atomic counters (everything else write-before-read)
    hipMemsetAsync(cnt, 0, (size_t)((char*)cur2 - (char*)cnt) + (size_t)maxN*4, stream);

    // ---- CSR build, both directions per launch ----
    int maxE = E1 > E2 ? E1 : E2;
    int nb1 = (Ng + 255)/256, nb2 = (Nm + 255)/256;
    int nbmax = nb1 > nb2 ? nb1 : nb2;
    hist2_k<<<dim3((maxE + 255)/256, 2), 256, 0, stream>>>(
        e_mg_dst, cnt, E1, Ng, e_gm_dst, cnt2, E2, Nm);
    scan_block2_k<<<dim3(nbmax, 2), 256, 0, stream>>>(
        cnt, incl, bsum, Ng, cnt2, incl2, bsum2, Nm);
    scan_top2_k<<<2, 512, 0, stream>>>(bsum, nb1, bsum2, nb2);
    finalize2_k<<<dim3(nbmax + 1, 2), 256, 0, stream>>>(
        incl, cnt, bsum, indptr_g, Ng, E1, incl2, cnt2, bsum2, indptr_m, Nm, E2);
    scatter2_k<<<dim3((maxE + 255)/256, 2), 256, 0, stream>>>(
        e_mg_src, e_mg_dst, indptr_g, cur, csr_mg, E1, Ng,
        e_gm_src, e_gm_dst, indptr_m, cur2, csr_gm, E2, Nm);

    // ---- unified weight prep (transposes + fused QKV weights), one launch ----
    wprep_k<<<2304, 128, 0, stream>>>(
        Wq_m, bq_m, Wk_m, bk_m, Wv_m, bv_m, a_mg, m_mg,
        Wq_g, bq_g, Wk_g, bk_g, Wv_g, bv_g, a_gm, m_gm,
        Wtf, bfv, Wa_m, Wa_g, W_out_m, W_out_g, Wta, Wtout);

    // ---- input projections (both sides, one launch) ----
    in_proj2_k<<<dim3(2048, 2), 128, 0, stream>>>(
        x_m, W_in_m, b_in_m, h_m, Nm,
        x_g, W_in_g, b_in_g, h_g, Ng);

    int gxm = (Nm + 63)/64, gxg = (Ng + 63)/64;
    int nbA = (Ng + 3)/4, nbB = (Nm + 3)/4;

    // ---- layers ----
    for (int l = 0; l < 2; ++l){
        // QKV: A staged once in LDS, 3x 128-col B chunks (reg-prefetched); split q/kv out
        mfma_gemm2<__hip_bfloat16, 1, 3><<<dim3(gxm + gxg, 1), 256, 0, stream>>>(
            h_m, Wtf + (size_t)(l*2+0)*49152, bfv + (l*2+0)*384,
            (__hip_bfloat16*)q_m, kv_m, Nm, nullptr,
            h_g, Wtf + (size_t)(l*2+1)*49152, bfv + (l*2+1)*384,
            (__hip_bfloat16*)q_g, kv_g, Ng, nullptr,
            0, gxm);

        edge_attn7_k<<<nbA + nbB, 256, 0, stream>>>(
            indptr_g, csr_mg, q_g, kv_m, p_mg + l*4, (unsigned*)agg_g, Ng,
            indptr_m, csr_gm, q_m, kv_g, p_gm + l*4, (unsigned*)agg_m, Nm,
            nbA);

        mfma_gemm2<float, 2, 1><<<dim3(gxm + gxg, 1), 256, 0, stream>>>(
            agg_m, Wta + (size_t)(l*2+0)*16384, ba_m + l*128, (float*)nullptr, h_m, Nm, skip_m + l,
            agg_g, Wta + (size_t)(l*2+1)*16384, ba_g + l*128, (float*)nullptr, h_g, Ng, skip_g + l,
            128, gxm);
    }

    // ---- output projections (fp32 out) ----
    float* outp = (float*)d_out;
    mfma_gemm2<float, 0, 1><<<dim3(gxm + gxg, 1), 256, 0, stream>>>(
        h_m, Wtout, b_out_m, outp, nullptr, Nm, nullptr,
        h_g, Wtout + 16384, b_out_g, outp + (size_t)Nm*128, nullptr, Ng, nullptr,
        128, gxm);
}

// Round 8
// 589.850 us; speedup vs baseline: 1.1037x; 1.1037x over previous
//
#include <hip/hip_runtime.h>
#include <hip/hip_bf16.h>

#define SCALE_F 0.17677669529663688f  // 1/sqrt(32)

typedef __attribute__((ext_vector_type(8)))  short bfrag;   // 8 bf16 = 4 VGPRs
typedef __attribute__((ext_vector_type(16))) float facc;    // 32x32 C/D: 16 fp32
typedef __attribute__((ext_vector_type(2)))  float f32x2;   // packs to v_pk_* on CDNA

extern "C" __device__ float __ocml_native_exp2_f32(float);  // bare v_exp_f32

__device__ __forceinline__ float lo16(unsigned u){ return __uint_as_float(u << 16); }
__device__ __forceinline__ float hi16(unsigned u){ return __uint_as_float(u & 0xffff0000u); }
__device__ __forceinline__ float bu2f(unsigned short u){ return __uint_as_float((unsigned)u << 16); }
__device__ __forceinline__ unsigned short f2bu(float f){
    __hip_bfloat16 h = __float2bfloat16(f);
    return *reinterpret_cast<unsigned short*>(&h);
}
__device__ __forceinline__ void storeC(float* p, float v){ *p = v; }
__device__ __forceinline__ void storeC(__hip_bfloat16* p, float v){ *p = __float2bfloat16(v); }

// ---------------- CSR build (dual-side kernels: blockIdx.y / blockIdx.x selects side) --
__global__ void hist2_k(const int* __restrict__ d1, int* __restrict__ c1, int E1, int N1,
                        const int* __restrict__ d2, int* __restrict__ c2, int E2, int N2){
    const int* d = blockIdx.y ? d2 : d1;
    int* c = blockIdx.y ? c2 : c1;
    int E = blockIdx.y ? E2 : E1;
    int Nd = blockIdx.y ? N2 : N1;
    int e = blockIdx.x*256 + threadIdx.x;
    if (e >= E) return;
    int dd = d[e];
    if ((unsigned)dd < (unsigned)Nd) atomicAdd(&c[dd], 1);
}

__global__ void scan_block2_k(const int* __restrict__ c1, int* __restrict__ i1, int* __restrict__ b1, int N1,
                              const int* __restrict__ c2, int* __restrict__ i2, int* __restrict__ b2, int N2){
    const int* cnt = blockIdx.y ? c2 : c1;
    int* incl = blockIdx.y ? i2 : i1;
    int* bsum = blockIdx.y ? b2 : b1;
    int N = blockIdx.y ? N2 : N1;
    if ((int)blockIdx.x*256 >= N) return;
    __shared__ int sh[256];
    int tid = threadIdx.x;
    int i = blockIdx.x*256 + tid;
    int v = (i < N) ? cnt[i] : 0;
    sh[tid] = v;
    __syncthreads();
    for (int off = 1; off < 256; off <<= 1){
        int t = (tid >= off) ? sh[tid-off] : 0;
        __syncthreads();
        sh[tid] += t;
        __syncthreads();
    }
    if (i < N) incl[i] = sh[tid];
    if (tid == 255) bsum[blockIdx.x] = sh[255];
}

__global__ void scan_top2_k(int* __restrict__ b1, int nb1, int* __restrict__ b2, int nb2){
    int* bsum = blockIdx.x ? b2 : b1;
    int nb = blockIdx.x ? nb2 : nb1;
    __shared__ int sh[512];
    int tid = threadIdx.x;
    int v = (tid < nb) ? bsum[tid] : 0;
    sh[tid] = v;
    __syncthreads();
    for (int off = 1; off < 512; off <<= 1){
        int t = (tid >= off) ? sh[tid-off] : 0;
        __syncthreads();
        sh[tid] += t;
        __syncthreads();
    }
    if (tid < nb) bsum[tid] = sh[tid] - v;  // exclusive
}

__global__ void finalize2_k(const int* __restrict__ i1, const int* __restrict__ c1,
                            const int* __restrict__ b1, int* __restrict__ p1, int N1, int E1,
                            const int* __restrict__ i2, const int* __restrict__ c2,
                            const int* __restrict__ b2, int* __restrict__ p2, int N2, int E2){
    const int* incl = blockIdx.y ? i2 : i1;
    const int* cnt  = blockIdx.y ? c2 : c1;
    const int* boff = blockIdx.y ? b2 : b1;
    int* indptr = blockIdx.y ? p2 : p1;
    int N = blockIdx.y ? N2 : N1;
    int E = blockIdx.y ? E2 : E1;
    int i = blockIdx.x*256 + threadIdx.x;
    if (i > N) return;
    if (i == N){ indptr[N] = E; return; }
    indptr[i] = boff[i >> 8] + incl[i] - cnt[i];
}

__global__ void scatter2_k(const int* __restrict__ s1, const int* __restrict__ d1,
                           const int* __restrict__ p1, int* __restrict__ u1,
                           int* __restrict__ r1, int E1, int N1,
                           const int* __restrict__ s2, const int* __restrict__ d2,
                           const int* __restrict__ p2, int* __restrict__ u2,
                           int* __restrict__ r2, int E2, int N2){
    const int* src = blockIdx.y ? s2 : s1;
    const int* dst = blockIdx.y ? d2 : d1;
    const int* indptr = blockIdx.y ? p2 : p1;
    int* cur = blockIdx.y ? u2 : u1;
    int* csr = blockIdx.y ? r2 : r1;
    int E = blockIdx.y ? E2 : E1;
    int Nd = blockIdx.y ? N2 : N1;
    int e = blockIdx.x*256 + threadIdx.x;
    if (e >= E) return;
    int d = dst[e];
    if ((unsigned)d >= (unsigned)Nd) return;
    int p = indptr[d] + atomicAdd(&cur[d], 1);
    csr[p] = src[e];
}

// ---------------- input projection: weight-stationary, LDS x-broadcast --------------
template<int K>
__device__ __forceinline__ void in_proj_body(const float* __restrict__ x,
                                             const float* __restrict__ W,
                                             const float* __restrict__ b,
                                             unsigned short* __restrict__ h, int N){
    constexpr int KP4 = (K + 3)/4, KP = KP4*4;
    int j = threadIdx.x;
    float wreg[KP];
    #pragma unroll
    for (int k = 0; k < KP; ++k) wreg[k] = (k < K) ? W[k*128 + j] : 0.f;
    float bj = b[j];
    __shared__ float xs[8][KP];
    for (int base = blockIdx.x*8; base < N; base += gridDim.x*8){
        __syncthreads();
        for (int t = threadIdx.x; t < 8*KP; t += 128){
            int r = t / KP, k = t - r*KP;
            int row = base + r;
            xs[r][k] = (row < N && k < K) ? x[(size_t)row*K + k] : 0.f;
        }
        __syncthreads();
        #pragma unroll
        for (int r = 0; r < 8; ++r){
            int row = base + r;
            if (row >= N) break;
            float acc = bj;
            #pragma unroll
            for (int kk = 0; kk < KP4; ++kk){
                float4 xv = *(const float4*)(&xs[r][kk*4]);
                acc += xv.x*wreg[kk*4] + xv.y*wreg[kk*4+1]
                     + xv.z*wreg[kk*4+2] + xv.w*wreg[kk*4+3];
            }
            h[(size_t)row*128 + j] = f2bu(acc);
        }
    }
}

__global__ __launch_bounds__(128) void in_proj2_k(
    const float* __restrict__ xm, const float* __restrict__ Wm,
    const float* __restrict__ bm_, unsigned short* __restrict__ hm, int Nm,
    const float* __restrict__ xg, const float* __restrict__ Wg,
    const float* __restrict__ bg_, unsigned short* __restrict__ hg, int Ng){
    if (blockIdx.y == 0) in_proj_body<20>(xm, Wm, bm_, hm, Nm);
    else                 in_proj_body<50>(xg, Wg, bg_, hg, Ng);
}

// ---------------- unified weight prep: QKV-fused weights (both layers, both sides)
// + 6-way 128x128 transposes, one launch ---------------------------------------------
__global__ __launch_bounds__(128) void wprep_k(
    const float* __restrict__ Wq_m, const float* __restrict__ bq_m,
    const float* __restrict__ Wk_m, const float* __restrict__ bk_m,
    const float* __restrict__ Wv_m, const float* __restrict__ bv_m,
    const float* __restrict__ a_mg, const float* __restrict__ m_mg,
    const float* __restrict__ Wq_g, const float* __restrict__ bq_g,
    const float* __restrict__ Wk_g, const float* __restrict__ bk_g,
    const float* __restrict__ Wv_g, const float* __restrict__ bv_g,
    const float* __restrict__ a_gm, const float* __restrict__ m_gm,
    unsigned short* __restrict__ Wtf, float* __restrict__ bfv,
    const float* __restrict__ Wa_m, const float* __restrict__ Wa_g,
    const float* __restrict__ W_out_m, const float* __restrict__ W_out_g,
    unsigned short* __restrict__ Wta, unsigned short* __restrict__ Wtout){
    int b = blockIdx.x;
    if (b < 1536){
        int u = b / 384, j = b % 384;
        int l = u >> 1;  bool sg = (u & 1);
        const float* Wq = (sg ? Wq_g : Wq_m) + l*16384;
        const float* bq = (sg ? bq_g : bq_m) + l*128;
        const float* Wk = (sg ? Wk_g : Wk_m) + l*16384;
        const float* bk = (sg ? bk_g : bk_m) + l*128;
        const float* Wv = (sg ? Wv_g : Wv_m) + l*16384;
        const float* bv = (sg ? bv_g : bv_m) + l*128;
        const float* ar = (sg ? a_gm : a_mg) + l*4096;
        const float* mr = (sg ? m_gm : m_mg) + l*4096;
        unsigned short* Wt = Wtf + (size_t)u*49152;
        float* bf = bfv + u*384;
        int row = threadIdx.x;
        int part = j >> 7, f = j & 127, hh = f >> 5, ff = f & 31;
        float v;
        if (part == 0) v = Wq[row*128 + f];
        else {
            const float* Wx  = (part == 1) ? Wk : Wv;
            const float* rel = (part == 1) ? ar : mr;
            float s = 0.f;
            #pragma unroll
            for (int d = 0; d < 32; ++d)
                s += Wx[row*128 + hh*32 + d] * rel[hh*1024 + d*32 + ff];
            v = s;
        }
        Wt[(size_t)j*128 + row] = f2bu(v);
        if (row == 0){
            float bb;
            if (part == 0) bb = bq[f];
            else {
                const float* bx  = (part == 1) ? bk : bv;
                const float* rel = (part == 1) ? ar : mr;
                float s = 0.f;
                for (int d = 0; d < 32; ++d)
                    s += bx[hh*32 + d] * rel[hh*1024 + d*32 + ff];
                bb = s;
            }
            bf[j] = bb;
        }
    } else {
        int t = b - 1536;
        int y = t >> 7;
        int idx = (t & 127)*128 + threadIdx.x;
        const float* S = (y==0)?Wa_m:(y==1)?Wa_g:(y==2)?(Wa_m+16384):(y==3)?(Wa_g+16384)
                        :(y==4)?W_out_m:W_out_g;
        unsigned short* D = (y==0)?Wta:(y==1)?(Wta+16384):(y==2)?(Wta+32768):(y==3)?(Wta+49152)
                           :(y==4)?Wtout:(Wtout+16384);
        int n = idx >> 7, k = idx & 127;
        D[idx] = f2bu(S[k*128 + n]);
    }
}

// ---------------- MFMA GEMM, two independent sides in one launch ---------------------
// C/D: col=lane&31, row=(reg&3)+8*(reg>>2)+4*(lane>>5)   [m74/m101 verified]
// FROZEN R4 structure (measured best over 4 experiments): 128-col chunks, 2
// accumulators/wave, LDS 52KB, 16 MFMAs per barrier pair, DIRECT global->LDS staging.
// Failed alternatives (do not retry): B-direct-from-L2 (R3, +13us/launch,
// stride-256B uncoalesced); 64-col chunks 4 blocks/CU (R6, -13us total, halves
// MFMA/barrier); register B-prefetch (R7, +47us, vmcnt drain before ds_write +
// 32 VGPR). Compiler's own staging schedule wins -- Common-mistake #5.
// MODE 0: plain store to C (ldc). MODE 1: split-QKV store (chunk 0 -> q[row*128],
// chunks 1,2 -> kv[row*256]; branch is chunk-uniform, constant-folds).
// MODE 2: skip-blend + ELU RMW on H.
template<typename CT, int MODE, int NCHUNK>
__global__ __launch_bounds__(256) void mfma_gemm2(
    const unsigned short* __restrict__ A0, const unsigned short* __restrict__ Wt0,
    const float* __restrict__ bias0, CT* __restrict__ C0, unsigned short* __restrict__ H0,
    int N0, const float* __restrict__ skip0,
    const unsigned short* __restrict__ A1, const unsigned short* __restrict__ Wt1,
    const float* __restrict__ bias1, CT* __restrict__ C1, unsigned short* __restrict__ H1,
    int N1, const float* __restrict__ skip1,
    int ldc, int nblk0){
    bool s0 = ((int)blockIdx.x < nblk0);
    const unsigned short* A  = s0 ? A0 : A1;
    const unsigned short* Wt = s0 ? Wt0 : Wt1;
    const float* bias = s0 ? bias0 : bias1;
    CT* C = s0 ? C0 : C1;
    unsigned short* H = s0 ? H0 : H1;
    int N = s0 ? N0 : N1;
    const float* skip = s0 ? skip0 : skip1;
    int bx = s0 ? blockIdx.x : (blockIdx.x - nblk0);

    __shared__ unsigned short As[64][136];
    __shared__ unsigned short Bs[128][136];
    int tid = threadIdx.x;
    int rb = bx*64;
    #pragma unroll
    for (int ph = 0; ph < 4; ++ph){
        int c = ph*256 + tid;
        int r = c >> 4, off = (c & 15)*8;
        uint4 v = make_uint4(0,0,0,0);
        if (rb + r < N) v = ((const uint4*)(A + (size_t)(rb + r)*128))[c & 15];
        *(uint4*)(&As[r][off]) = v;
    }
    int w = tid >> 6, lane = tid & 63;
    int wr = (w >> 1)*32, wc = (w & 1)*64;
    int m = lane & 31, quad = lane >> 5;
    const unsigned short* ap  = &As[wr + m][quad*8];
    const unsigned short* bp0 = &Bs[wc + m][quad*8];
    const unsigned short* bp1 = &Bs[wc + 32 + m][quad*8];
    float bm = 0.f;
    if (MODE == 2) bm = 1.f/(1.f + __expf(-skip[0]));

    #pragma unroll
    for (int chunk = 0; chunk < NCHUNK; ++chunk){
        int cb = chunk*128;
        if (chunk > 0) __syncthreads();   // all waves done reading Bs of prev chunk
        #pragma unroll
        for (int ph = 0; ph < 8; ++ph){
            int c = ph*256 + tid;
            int r = c >> 4, off = (c & 15)*8;
            uint4 v = ((const uint4*)(Wt + (size_t)(cb + r)*128))[c & 15];
            *(uint4*)(&Bs[r][off]) = v;
        }
        __syncthreads();                   // covers As on chunk 0 as well
        facc acc0, acc1;
        #pragma unroll
        for (int i = 0; i < 16; ++i){ acc0[i] = 0.f; acc1[i] = 0.f; }
        #pragma unroll
        for (int kc = 0; kc < 8; ++kc){
            bfrag a  = *(const bfrag*)(ap  + kc*16);
            bfrag b0 = *(const bfrag*)(bp0 + kc*16);
            bfrag b1 = *(const bfrag*)(bp1 + kc*16);
            acc0 = __builtin_amdgcn_mfma_f32_32x32x16_bf16(a, b0, acc0, 0, 0, 0);
            acc1 = __builtin_amdgcn_mfma_f32_32x32x16_bf16(a, b1, acc1, 0, 0, 0);
        }
        int col0 = cb + wc + m, col1 = col0 + 32;
        float bias0v = bias[col0], bias1v = bias[col1];
        #pragma unroll
        for (int r = 0; r < 16; ++r){
            int lrow = wr + 4*quad + (r & 3) + 8*(r >> 2);
            int grow = rb + lrow;
            if (grow >= N) continue;
            float o0 = acc0[r] + bias0v;
            float o1 = acc1[r] + bias1v;
            if (MODE == 0){
                storeC(&C[(size_t)grow*ldc + col0], o0);
                storeC(&C[(size_t)grow*ldc + col1], o1);
            } else if (MODE == 1){
                unsigned short* qp = (unsigned short*)C;
                if (col0 < 128){
                    qp[(size_t)grow*128 + col0] = f2bu(o0);
                    qp[(size_t)grow*128 + col1] = f2bu(o1);
                } else {
                    H[(size_t)grow*256 + (col0 - 128)] = f2bu(o0);
                    H[(size_t)grow*256 + (col1 - 128)] = f2bu(o1);
                }
            } else {
                size_t i0 = (size_t)grow*128 + col0, i1 = (size_t)grow*128 + col1;
                float v0 = bm*o0 + (1.f - bm)*bu2f(H[i0]);
                float v1 = bm*o1 + (1.f - bm)*bu2f(H[i1]);
                v0 = (v0 > 0.f) ? v0 : expm1f(v0);
                v1 = (v1 > 0.f) ? v1 : expm1f(v1);
                H[i0] = f2bu(v0);
                H[i1] = f2bu(v1);
            }
        }
    }
}

// ---------------- edge attention v7: split q/kv layout ------------------------------
// q row = 128 bf16 (256B); kv row = 256 bf16 (512B contiguous: kt [0:256)B, vt [256:512)B).
// Measured 76.5us (R6/R7) vs 79.0 (R4 768B-stride layout) -- keep. FETCH unchanged
// (224.8MB): the win was address-arithmetic simplicity, not traffic.
// Lane (slot=lane>>4, j=lane&15): 8 dims (uint4 j) of slot's edge; head = j>>2.
// 2-deep pipeline (csr 2 ahead, K/V 1 ahead) -- measured optimum (R2: 3-deep regressed).
__global__ __launch_bounds__(256) void edge_attn7_k(
    const int* __restrict__ ipA, const int* __restrict__ csrA,
    const unsigned short* __restrict__ qdA, const unsigned short* __restrict__ kvA,
    const float* __restrict__ pA, unsigned* __restrict__ aggA, int NdA,
    const int* __restrict__ ipB, const int* __restrict__ csrB,
    const unsigned short* __restrict__ qdB, const unsigned short* __restrict__ kvB,
    const float* __restrict__ pB, unsigned* __restrict__ aggB, int NdB,
    int nblkA){
    bool sA = ((int)blockIdx.x < nblkA);
    const int* ip  = sA ? ipA : ipB;
    const int* csr = sA ? csrA : csrB;
    const uint4* qd = (const uint4*)(sA ? qdA : qdB);
    const char* kvc = (const char*)(sA ? kvA : kvB);
    const float* p = sA ? pA : pB;
    unsigned* agg = sA ? aggA : aggB;
    int Nd = sA ? NdA : NdB;
    int bx = sA ? blockIdx.x : (blockIdx.x - nblkA);
    int wid  = (bx << 2) | (threadIdx.x >> 6);
    int lane = threadIdx.x & 63;
    if (wid >= Nd) return;
    int slot = lane >> 4, j = lane & 15;
    // fold log2(e) into the per-head scale: exp(x) == exp2(x*log2e) -> bare v_exp_f32
    float phL = p[j >> 2] * (SCALE_F * 1.4426950408889634f);
    uint4 qv = qd[(size_t)wid*16 + j];
    f32x2 q2[4];
    q2[0] = (f32x2){lo16(qv.x), hi16(qv.x)};
    q2[1] = (f32x2){lo16(qv.y), hi16(qv.y)};
    q2[2] = (f32x2){lo16(qv.z), hi16(qv.z)};
    q2[3] = (f32x2){lo16(qv.w), hi16(qv.w)};
    int beg = ip[wid], end = ip[wid + 1];
    float den = 0.f;
    f32x2 acc2[4] = {};
    int loff = j*16;
    int i0 = beg + slot;
    if (i0 < end){
        int s0c = csr[i0];
        int i1 = i0 + 4;
        bool m1 = (i1 < end);
        int s1 = m1 ? csr[i1] : 0;          // csr one ahead, ready before loop
        const char* b0 = kvc + (size_t)s0c*512 + loff;
        uint4 kv = *(const uint4*)(b0);
        uint4 vv = *(const uint4*)(b0 + 256);
        while (true){
            // csr TWO ahead; K/V ONE ahead with address already in registers
            int i2 = i1 + 4;
            bool m2 = (i2 < end);
            int s2 = m2 ? csr[i2] : 0;
            uint4 kv2, vv2;
            if (m1){
                const char* b1 = kvc + (size_t)s1*512 + loff;
                kv2 = *(const uint4*)(b1);
                vv2 = *(const uint4*)(b1 + 256);
            }
            f32x2 pp = q2[0] * (f32x2){lo16(kv.x), hi16(kv.x)};
            pp += q2[1] * (f32x2){lo16(kv.y), hi16(kv.y)};
            pp += q2[2] * (f32x2){lo16(kv.z), hi16(kv.z)};
            pp += q2[3] * (f32x2){lo16(kv.w), hi16(kv.w)};
            float part = pp.x + pp.y;
            part += __shfl_xor(part, 1);   // reduce within 4-lane head group
            part += __shfl_xor(part, 2);
            float e = __ocml_native_exp2_f32(part * phL);
            den += e;
            acc2[0] += (f32x2){lo16(vv.x), hi16(vv.x)} * e;
            acc2[1] += (f32x2){lo16(vv.y), hi16(vv.y)} * e;
            acc2[2] += (f32x2){lo16(vv.z), hi16(vv.z)} * e;
            acc2[3] += (f32x2){lo16(vv.w), hi16(vv.w)} * e;
            if (!m1) break;
            kv = kv2; vv = vv2;
            i1 = i2; m1 = m2; s1 = s2;
        }
    }
    // cross-slot reduce (slots hold disjoint edge subsets)
    den += __shfl_xor(den, 16);
    den += __shfl_xor(den, 32);
    #pragma unroll
    for (int k = 0; k < 4; ++k){
        f32x2 t;
        t.x = __shfl_xor(acc2[k].x, 16);
        t.y = __shfl_xor(acc2[k].y, 16);
        acc2[k] += t;
        t.x = __shfl_xor(acc2[k].x, 32);
        t.y = __shfl_xor(acc2[k].y, 32);
        acc2[k] += t;
    }
    float inv = (den > 0.f) ? 1.f/den : 0.f;
    // epilogue: each lane handles dims {8j + 2*slot, 8j + 2*slot + 1} = acc2[slot]
    f32x2 sel = (slot & 2) ? ((slot & 1) ? acc2[3] : acc2[2])
                           : ((slot & 1) ? acc2[1] : acc2[0]);
    float o0 = sel.x*inv, o1 = sel.y*inv;
    o0 = 0.5f*o0*(1.f + erff(o0*0.70710678118654752f));
    o1 = 0.5f*o1*(1.f + erff(o1*0.70710678118654752f));
    agg[(size_t)wid*64 + j*4 + slot] = (unsigned)f2bu(o0) | ((unsigned)f2bu(o1) << 16);
}

// ---------------- host launcher ----------------
extern "C" void kernel_launch(void* const* d_in, const int* in_sizes, int n_in,
                              void* d_out, int out_size, void* d_ws, size_t ws_size,
                              hipStream_t stream){
    typedef const float* FP;
    FP x_m = (FP)d_in[0], x_g = (FP)d_in[1];
    FP W_in_m = (FP)d_in[2], b_in_m = (FP)d_in[3], W_in_g = (FP)d_in[4], b_in_g = (FP)d_in[5];
    FP Wk_m = (FP)d_in[6],  bk_m = (FP)d_in[7],  Wq_m = (FP)d_in[8],  bq_m = (FP)d_in[9];
    FP Wv_m = (FP)d_in[10], bv_m = (FP)d_in[11];
    FP Wk_g = (FP)d_in[12], bk_g = (FP)d_in[13], Wq_g = (FP)d_in[14], bq_g = (FP)d_in[15];
    FP Wv_g = (FP)d_in[16], bv_g = (FP)d_in[17];
    FP a_mg = (FP)d_in[18], m_mg = (FP)d_in[19], p_mg = (FP)d_in[20];
    FP a_gm = (FP)d_in[21], m_gm = (FP)d_in[22], p_gm = (FP)d_in[23];
    FP Wa_m = (FP)d_in[24], ba_m = (FP)d_in[25], Wa_g = (FP)d_in[26], ba_g = (FP)d_in[27];
    FP skip_m = (FP)d_in[28], skip_g = (FP)d_in[29];
    FP W_out_m = (FP)d_in[30], b_out_m = (FP)d_in[31], W_out_g = (FP)d_in[32], b_out_g = (FP)d_in[33];
    const int* e_mg_src = (const int*)d_in[34];
    const int* e_mg_dst = (const int*)d_in[35];
    const int* e_gm_src = (const int*)d_in[36];
    const int* e_gm_dst = (const int*)d_in[37];

    const int Nm = in_sizes[0] / 20;
    const int Ng = in_sizes[1] / 50;
    const int E1 = in_sizes[34];   // m -> g
    const int E2 = in_sizes[36];   // g -> m

    // ---- workspace carve (256B aligned) ----
    char* wp = (char*)d_ws;
    auto alloc = [&](size_t bytes) -> char* {
        char* r = wp; wp += (bytes + 255) & ~(size_t)255; return r;
    };
    unsigned short* h_m   = (unsigned short*)alloc((size_t)Nm*128*2);
    unsigned short* h_g   = (unsigned short*)alloc((size_t)Ng*128*2);
    unsigned short* agg_m = (unsigned short*)alloc((size_t)Nm*128*2);
    unsigned short* agg_g = (unsigned short*)alloc((size_t)Ng*128*2);
    unsigned short* q_m   = (unsigned short*)alloc((size_t)Nm*128*2);
    unsigned short* kv_m  = (unsigned short*)alloc((size_t)Nm*256*2);
    unsigned short* q_g   = (unsigned short*)alloc((size_t)Ng*128*2);
    unsigned short* kv_g  = (unsigned short*)alloc((size_t)Ng*256*2);
    unsigned short* Wtf   = (unsigned short*)alloc((size_t)4*49152*2);  // [l*2+side][384][128]
    float*          bfv   = (float*)alloc((size_t)4*384*4);
    unsigned short* Wta   = (unsigned short*)alloc((size_t)4*16384*2);  // [l*2+side]
    unsigned short* Wtout = (unsigned short*)alloc((size_t)2*16384*2);
    int* indptr_g = (int*)alloc((size_t)(Ng+1)*4);
    int* csr_mg   = (int*)alloc((size_t)E1*4);
    int* indptr_m = (int*)alloc((size_t)(Nm+1)*4);
    int* csr_gm   = (int*)alloc((size_t)E2*4);
    int maxN = Nm > Ng ? Nm : Ng;
    int* cnt  = (int*)alloc((size_t)maxN*4);
    int* cur  = (int*)alloc((size_t)maxN*4);
    int* cnt2 = (int*)alloc((size_t)maxN*4);
    int* cur2 = (int*)alloc((size_t)maxN*4);
    int* incl = (int*)alloc((size_t)maxN*4);
    int* incl2= (int*)alloc((size_t)maxN*4);
    int* bsum = (int*)alloc(512*4);
    int* bsum2= (int*)alloc(512*4);

    size_t used = (size_t)(wp - (char*)d_ws);
    if (used > ws_size){
        hipMemsetAsync(d_out, 0, (size_t)out_size*4, stream);
        return;
    }
    // zero only the atomic counters (everything else write-before-read)
    hipMemsetAsync(cnt, 0, (size_t)((char*)cur2 - (char*)cnt) + (size_t)maxN*4, stream);

    // ---- CSR build, both directions per launch ----
    int maxE = E1 > E2 ? E1 : E2;
    int nb1 = (Ng + 255)/256, nb2 = (Nm + 255)/256;
    int nbmax = nb1 > nb2 ? nb1 : nb2;
    hist2_k<<<dim3((maxE + 255)/256, 2), 256, 0, stream>>>(
        e_mg_dst, cnt, E1, Ng, e_gm_dst, cnt2, E2, Nm);
    scan_block2_k<<<dim3(nbmax, 2), 256, 0, stream>>>(
        cnt, incl, bsum, Ng, cnt2, incl2, bsum2, Nm);
    scan_top2_k<<<2, 512, 0, stream>>>(bsum, nb1, bsum2, nb2);
    finalize2_k<<<dim3(nbmax + 1, 2), 256, 0, stream>>>(
        incl, cnt, bsum, indptr_g, Ng, E1, incl2, cnt2, bsum2, indptr_m, Nm, E2);
    scatter2_k<<<dim3((maxE + 255)/256, 2), 256, 0, stream>>>(
        e_mg_src, e_mg_dst, indptr_g, cur, csr_mg, E1, Ng,
        e_gm_src, e_gm_dst, indptr_m, cur2, csr_gm, E2, Nm);

    // ---- unified weight prep (transposes + fused QKV weights), one launch ----
    wprep_k<<<2304, 128, 0, stream>>>(
        Wq_m, bq_m, Wk_m, bk_m, Wv_m, bv_m, a_mg, m_mg,
        Wq_g, bq_g, Wk_g, bk_g, Wv_g, bv_g, a_gm, m_gm,
        Wtf, bfv, Wa_m, Wa_g, W_out_m, W_out_g, Wta, Wtout);

    // ---- input projections (both sides, one launch) ----
    in_proj2_k<<<dim3(2048, 2), 128, 0, stream>>>(
        x_m, W_in_m, b_in_m, h_m, Nm,
        x_g, W_in_g, b_in_g, h_g, Ng);

    int gxm = (Nm + 63)/64, gxg = (Ng + 63)/64;
    int nbA = (Ng + 3)/4, nbB = (Nm + 3)/4;

    // ---- layers ----
    for (int l = 0; l < 2; ++l){
        // QKV: A staged once in LDS, 3x 128-col B chunks (direct staging); split q/kv out
        mfma_gemm2<__hip_bfloat16, 1, 3><<<dim3(gxm + gxg, 1), 256, 0, stream>>>(
            h_m, Wtf + (size_t)(l*2+0)*49152, bfv + (l*2+0)*384,
            (__hip_bfloat16*)q_m, kv_m, Nm, nullptr,
            h_g, Wtf + (size_t)(l*2+1)*49152, bfv + (l*2+1)*384,
            (__hip_bfloat16*)q_g, kv_g, Ng, nullptr,
            0, gxm);

        edge_attn7_k<<<nbA + nbB, 256, 0, stream>>>(
            indptr_g, csr_mg, q_g, kv_m, p_mg + l*4, (unsigned*)agg_g, Ng,
            indptr_m, csr_gm, q_m, kv_g, p_gm + l*4, (unsigned*)agg_m, Nm,
            nbA);

        mfma_gemm2<float, 2, 1><<<dim3(gxm + gxg, 1), 256, 0, stream>>>(
            agg_m, Wta + (size_t)(l*2+0)*16384, ba_m + l*128, (float*)nullptr, h_m, Nm, skip_m + l,
            agg_g, Wta + (size_t)(l*2+1)*16384, ba_g + l*128, (float*)nullptr, h_g, Ng, skip_g + l,
            128, gxm);
    }

    // ---- output projections (fp32 out) ----
    float* outp = (float*)d_out;
    mfma_gemm2<float, 0, 1><<<dim3(gxm + gxg, 1), 256, 0, stream>>>(
        h_m, Wtout, b_out_m, outp, nullptr, Nm, nullptr,
        h_g, Wtout + 16384, b_out_g, outp + (size_t)Nm*128, nullptr, Ng, nullptr,
        128, gxm);
}

// Round 9
// 583.907 us; speedup vs baseline: 1.1149x; 1.0102x over previous
//
#include <hip/hip_runtime.h>
#include <hip/hip_bf16.h>

#define SCALE_F 0.17677669529663688f  // 1/sqrt(32)

typedef __attribute__((ext_vector_type(8)))  short bfrag;   // 8 bf16 = 4 VGPRs
typedef __attribute__((ext_vector_type(16))) float facc;    // 32x32 C/D: 16 fp32
typedef __attribute__((ext_vector_type(2)))  float f32x2;   // packs to v_pk_* on CDNA

extern "C" __device__ float __ocml_native_exp2_f32(float);  // bare v_exp_f32

__device__ __forceinline__ float lo16(unsigned u){ return __uint_as_float(u << 16); }
__device__ __forceinline__ float hi16(unsigned u){ return __uint_as_float(u & 0xffff0000u); }
__device__ __forceinline__ float bu2f(unsigned short u){ return __uint_as_float((unsigned)u << 16); }
__device__ __forceinline__ unsigned short f2bu(float f){
    __hip_bfloat16 h = __float2bfloat16(f);
    return *reinterpret_cast<unsigned short*>(&h);
}
__device__ __forceinline__ void storeC(float* p, float v){ *p = v; }
__device__ __forceinline__ void storeC(__hip_bfloat16* p, float v){ *p = __float2bfloat16(v); }

// ---------------- CSR build (dual-side kernels: blockIdx.y / blockIdx.x selects side) --
__global__ void hist2_k(const int* __restrict__ d1, int* __restrict__ c1, int E1, int N1,
                        const int* __restrict__ d2, int* __restrict__ c2, int E2, int N2){
    const int* d = blockIdx.y ? d2 : d1;
    int* c = blockIdx.y ? c2 : c1;
    int E = blockIdx.y ? E2 : E1;
    int Nd = blockIdx.y ? N2 : N1;
    int e = blockIdx.x*256 + threadIdx.x;
    if (e >= E) return;
    int dd = d[e];
    if ((unsigned)dd < (unsigned)Nd) atomicAdd(&c[dd], 1);
}

__global__ void scan_block2_k(const int* __restrict__ c1, int* __restrict__ i1, int* __restrict__ b1, int N1,
                              const int* __restrict__ c2, int* __restrict__ i2, int* __restrict__ b2, int N2){
    const int* cnt = blockIdx.y ? c2 : c1;
    int* incl = blockIdx.y ? i2 : i1;
    int* bsum = blockIdx.y ? b2 : b1;
    int N = blockIdx.y ? N2 : N1;
    if ((int)blockIdx.x*256 >= N) return;
    __shared__ int sh[256];
    int tid = threadIdx.x;
    int i = blockIdx.x*256 + tid;
    int v = (i < N) ? cnt[i] : 0;
    sh[tid] = v;
    __syncthreads();
    for (int off = 1; off < 256; off <<= 1){
        int t = (tid >= off) ? sh[tid-off] : 0;
        __syncthreads();
        sh[tid] += t;
        __syncthreads();
    }
    if (i < N) incl[i] = sh[tid];
    if (tid == 255) bsum[blockIdx.x] = sh[255];
}

__global__ void scan_top2_k(int* __restrict__ b1, int nb1, int* __restrict__ b2, int nb2){
    int* bsum = blockIdx.x ? b2 : b1;
    int nb = blockIdx.x ? nb2 : nb1;
    __shared__ int sh[512];
    int tid = threadIdx.x;
    int v = (tid < nb) ? bsum[tid] : 0;
    sh[tid] = v;
    __syncthreads();
    for (int off = 1; off < 512; off <<= 1){
        int t = (tid >= off) ? sh[tid-off] : 0;
        __syncthreads();
        sh[tid] += t;
        __syncthreads();
    }
    if (tid < nb) bsum[tid] = sh[tid] - v;  // exclusive
}

__global__ void finalize2_k(const int* __restrict__ i1, const int* __restrict__ c1,
                            const int* __restrict__ b1, int* __restrict__ p1, int N1, int E1,
                            const int* __restrict__ i2, const int* __restrict__ c2,
                            const int* __restrict__ b2, int* __restrict__ p2, int N2, int E2){
    const int* incl = blockIdx.y ? i2 : i1;
    const int* cnt  = blockIdx.y ? c2 : c1;
    const int* boff = blockIdx.y ? b2 : b1;
    int* indptr = blockIdx.y ? p2 : p1;
    int N = blockIdx.y ? N2 : N1;
    int E = blockIdx.y ? E2 : E1;
    int i = blockIdx.x*256 + threadIdx.x;
    if (i > N) return;
    if (i == N){ indptr[N] = E; return; }
    indptr[i] = boff[i >> 8] + incl[i] - cnt[i];
}

__global__ void scatter2_k(const int* __restrict__ s1, const int* __restrict__ d1,
                           const int* __restrict__ p1, int* __restrict__ u1,
                           int* __restrict__ r1, int E1, int N1,
                           const int* __restrict__ s2, const int* __restrict__ d2,
                           const int* __restrict__ p2, int* __restrict__ u2,
                           int* __restrict__ r2, int E2, int N2){
    const int* src = blockIdx.y ? s2 : s1;
    const int* dst = blockIdx.y ? d2 : d1;
    const int* indptr = blockIdx.y ? p2 : p1;
    int* cur = blockIdx.y ? u2 : u1;
    int* csr = blockIdx.y ? r2 : r1;
    int E = blockIdx.y ? E2 : E1;
    int Nd = blockIdx.y ? N2 : N1;
    int e = blockIdx.x*256 + threadIdx.x;
    if (e >= E) return;
    int d = dst[e];
    if ((unsigned)d >= (unsigned)Nd) return;
    int p = indptr[d] + atomicAdd(&cur[d], 1);
    csr[p] = src[e];
}

// ---------------- input projection: weight-stationary, LDS x-broadcast --------------
template<int K>
__device__ __forceinline__ void in_proj_body(const float* __restrict__ x,
                                             const float* __restrict__ W,
                                             const float* __restrict__ b,
                                             unsigned short* __restrict__ h, int N){
    constexpr int KP4 = (K + 3)/4, KP = KP4*4;
    int j = threadIdx.x;
    float wreg[KP];
    #pragma unroll
    for (int k = 0; k < KP; ++k) wreg[k] = (k < K) ? W[k*128 + j] : 0.f;
    float bj = b[j];
    __shared__ float xs[8][KP];
    for (int base = blockIdx.x*8; base < N; base += gridDim.x*8){
        __syncthreads();
        for (int t = threadIdx.x; t < 8*KP; t += 128){
            int r = t / KP, k = t - r*KP;
            int row = base + r;
            xs[r][k] = (row < N && k < K) ? x[(size_t)row*K + k] : 0.f;
        }
        __syncthreads();
        #pragma unroll
        for (int r = 0; r < 8; ++r){
            int row = base + r;
            if (row >= N) break;
            float acc = bj;
            #pragma unroll
            for (int kk = 0; kk < KP4; ++kk){
                float4 xv = *(const float4*)(&xs[r][kk*4]);
                acc += xv.x*wreg[kk*4] + xv.y*wreg[kk*4+1]
                     + xv.z*wreg[kk*4+2] + xv.w*wreg[kk*4+3];
            }
            h[(size_t)row*128 + j] = f2bu(acc);
        }
    }
}

__global__ __launch_bounds__(128) void in_proj2_k(
    const float* __restrict__ xm, const float* __restrict__ Wm,
    const float* __restrict__ bm_, unsigned short* __restrict__ hm, int Nm,
    const float* __restrict__ xg, const float* __restrict__ Wg,
    const float* __restrict__ bg_, unsigned short* __restrict__ hg, int Ng){
    if (blockIdx.y == 0) in_proj_body<20>(xm, Wm, bm_, hm, Nm);
    else                 in_proj_body<50>(xg, Wg, bg_, hg, Ng);
}

// ---------------- unified weight prep: QKV-fused weights (both layers, both sides)
// + 6-way 128x128 transposes, one launch ---------------------------------------------
__global__ __launch_bounds__(128) void wprep_k(
    const float* __restrict__ Wq_m, const float* __restrict__ bq_m,
    const float* __restrict__ Wk_m, const float* __restrict__ bk_m,
    const float* __restrict__ Wv_m, const float* __restrict__ bv_m,
    const float* __restrict__ a_mg, const float* __restrict__ m_mg,
    const float* __restrict__ Wq_g, const float* __restrict__ bq_g,
    const float* __restrict__ Wk_g, const float* __restrict__ bk_g,
    const float* __restrict__ Wv_g, const float* __restrict__ bv_g,
    const float* __restrict__ a_gm, const float* __restrict__ m_gm,
    unsigned short* __restrict__ Wtf, float* __restrict__ bfv,
    const float* __restrict__ Wa_m, const float* __restrict__ Wa_g,
    const float* __restrict__ W_out_m, const float* __restrict__ W_out_g,
    unsigned short* __restrict__ Wta, unsigned short* __restrict__ Wtout){
    int b = blockIdx.x;
    if (b < 1536){
        int u = b / 384, j = b % 384;
        int l = u >> 1;  bool sg = (u & 1);
        const float* Wq = (sg ? Wq_g : Wq_m) + l*16384;
        const float* bq = (sg ? bq_g : bq_m) + l*128;
        const float* Wk = (sg ? Wk_g : Wk_m) + l*16384;
        const float* bk = (sg ? bk_g : bk_m) + l*128;
        const float* Wv = (sg ? Wv_g : Wv_m) + l*16384;
        const float* bv = (sg ? bv_g : bv_m) + l*128;
        const float* ar = (sg ? a_gm : a_mg) + l*4096;
        const float* mr = (sg ? m_gm : m_mg) + l*4096;
        unsigned short* Wt = Wtf + (size_t)u*49152;
        float* bf = bfv + u*384;
        int row = threadIdx.x;
        int part = j >> 7, f = j & 127, hh = f >> 5, ff = f & 31;
        float v;
        if (part == 0) v = Wq[row*128 + f];
        else {
            const float* Wx  = (part == 1) ? Wk : Wv;
            const float* rel = (part == 1) ? ar : mr;
            float s = 0.f;
            #pragma unroll
            for (int d = 0; d < 32; ++d)
                s += Wx[row*128 + hh*32 + d] * rel[hh*1024 + d*32 + ff];
            v = s;
        }
        Wt[(size_t)j*128 + row] = f2bu(v);
        if (row == 0){
            float bb;
            if (part == 0) bb = bq[f];
            else {
                const float* bx  = (part == 1) ? bk : bv;
                const float* rel = (part == 1) ? ar : mr;
                float s = 0.f;
                for (int d = 0; d < 32; ++d)
                    s += bx[hh*32 + d] * rel[hh*1024 + d*32 + ff];
                bb = s;
            }
            bf[j] = bb;
        }
    } else {
        int t = b - 1536;
        int y = t >> 7;
        int idx = (t & 127)*128 + threadIdx.x;
        const float* S = (y==0)?Wa_m:(y==1)?Wa_g:(y==2)?(Wa_m+16384):(y==3)?(Wa_g+16384)
                        :(y==4)?W_out_m:W_out_g;
        unsigned short* D = (y==0)?Wta:(y==1)?(Wta+16384):(y==2)?(Wta+32768):(y==3)?(Wta+49152)
                           :(y==4)?Wtout:(Wtout+16384);
        int n = idx >> 7, k = idx & 127;
        D[idx] = f2bu(S[k*128 + n]);
    }
}

// ---------------- MFMA GEMM, two independent sides in one launch ---------------------
// C/D: col=lane&31, row=(reg&3)+8*(reg>>2)+4*(lane>>5)   [m74/m101 verified]
// FROZEN R4 structure (measured best over 4 experiments): 128-col chunks, 2
// accumulators/wave, LDS 52KB, 16 MFMAs per barrier pair, DIRECT global->LDS staging.
// Failed alternatives (do not retry): B-direct-from-L2 (R3, +13us/launch,
// stride-256B uncoalesced); 64-col chunks 4 blocks/CU (R6, -13us total, halves
// MFMA/barrier); register B-prefetch (R7, +47us, vmcnt drain before ds_write +
// 32 VGPR). Compiler's own staging schedule wins -- Common-mistake #5.
// MODE 0: plain store to C (ldc). MODE 1: split-QKV store (chunk 0 -> q[row*128],
// chunks 1,2 -> kv[row*256]). MODE 2: skip-blend + ELU RMW on H.
template<typename CT, int MODE, int NCHUNK>
__global__ __launch_bounds__(256) void mfma_gemm2(
    const unsigned short* __restrict__ A0, const unsigned short* __restrict__ Wt0,
    const float* __restrict__ bias0, CT* __restrict__ C0, unsigned short* __restrict__ H0,
    int N0, const float* __restrict__ skip0,
    const unsigned short* __restrict__ A1, const unsigned short* __restrict__ Wt1,
    const float* __restrict__ bias1, CT* __restrict__ C1, unsigned short* __restrict__ H1,
    int N1, const float* __restrict__ skip1,
    int ldc, int nblk0){
    bool s0 = ((int)blockIdx.x < nblk0);
    const unsigned short* A  = s0 ? A0 : A1;
    const unsigned short* Wt = s0 ? Wt0 : Wt1;
    const float* bias = s0 ? bias0 : bias1;
    CT* C = s0 ? C0 : C1;
    unsigned short* H = s0 ? H0 : H1;
    int N = s0 ? N0 : N1;
    const float* skip = s0 ? skip0 : skip1;
    int bx = s0 ? blockIdx.x : (blockIdx.x - nblk0);

    __shared__ unsigned short As[64][136];
    __shared__ unsigned short Bs[128][136];
    int tid = threadIdx.x;
    int rb = bx*64;
    #pragma unroll
    for (int ph = 0; ph < 4; ++ph){
        int c = ph*256 + tid;
        int r = c >> 4, off = (c & 15)*8;
        uint4 v = make_uint4(0,0,0,0);
        if (rb + r < N) v = ((const uint4*)(A + (size_t)(rb + r)*128))[c & 15];
        *(uint4*)(&As[r][off]) = v;
    }
    int w = tid >> 6, lane = tid & 63;
    int wr = (w >> 1)*32, wc = (w & 1)*64;
    int m = lane & 31, quad = lane >> 5;
    const unsigned short* ap  = &As[wr + m][quad*8];
    const unsigned short* bp0 = &Bs[wc + m][quad*8];
    const unsigned short* bp1 = &Bs[wc + 32 + m][quad*8];
    float bm = 0.f;
    if (MODE == 2) bm = 1.f/(1.f + __expf(-skip[0]));

    #pragma unroll
    for (int chunk = 0; chunk < NCHUNK; ++chunk){
        int cb = chunk*128;
        if (chunk > 0) __syncthreads();   // all waves done reading Bs of prev chunk
        #pragma unroll
        for (int ph = 0; ph < 8; ++ph){
            int c = ph*256 + tid;
            int r = c >> 4, off = (c & 15)*8;
            uint4 v = ((const uint4*)(Wt + (size_t)(cb + r)*128))[c & 15];
            *(uint4*)(&Bs[r][off]) = v;
        }
        __syncthreads();                   // covers As on chunk 0 as well
        facc acc0, acc1;
        #pragma unroll
        for (int i = 0; i < 16; ++i){ acc0[i] = 0.f; acc1[i] = 0.f; }
        #pragma unroll
        for (int kc = 0; kc < 8; ++kc){
            bfrag a  = *(const bfrag*)(ap  + kc*16);
            bfrag b0 = *(const bfrag*)(bp0 + kc*16);
            bfrag b1 = *(const bfrag*)(bp1 + kc*16);
            acc0 = __builtin_amdgcn_mfma_f32_32x32x16_bf16(a, b0, acc0, 0, 0, 0);
            acc1 = __builtin_amdgcn_mfma_f32_32x32x16_bf16(a, b1, acc1, 0, 0, 0);
        }
        int col0 = cb + wc + m, col1 = col0 + 32;
        float bias0v = bias[col0], bias1v = bias[col1];
        #pragma unroll
        for (int r = 0; r < 16; ++r){
            int lrow = wr + 4*quad + (r & 3) + 8*(r >> 2);
            int grow = rb + lrow;
            if (grow >= N) continue;
            float o0 = acc0[r] + bias0v;
            float o1 = acc1[r] + bias1v;
            if (MODE == 0){
                storeC(&C[(size_t)grow*ldc + col0], o0);
                storeC(&C[(size_t)grow*ldc + col1], o1);
            } else if (MODE == 1){
                unsigned short* qp = (unsigned short*)C;
                if (col0 < 128){
                    qp[(size_t)grow*128 + col0] = f2bu(o0);
                    qp[(size_t)grow*128 + col1] = f2bu(o1);
                } else {
                    H[(size_t)grow*256 + (col0 - 128)] = f2bu(o0);
                    H[(size_t)grow*256 + (col1 - 128)] = f2bu(o1);
                }
            } else {
                size_t i0 = (size_t)grow*128 + col0, i1 = (size_t)grow*128 + col1;
                float v0 = bm*o0 + (1.f - bm)*bu2f(H[i0]);
                float v1 = bm*o1 + (1.f - bm)*bu2f(H[i1]);
                v0 = (v0 > 0.f) ? v0 : expm1f(v0);
                v1 = (v1 > 0.f) ? v1 : expm1f(v1);
                H[i0] = f2bu(v0);
                H[i1] = f2bu(v1);
            }
        }
    }
}

// ---------------- fused last-layer attn-out + output projection ----------------------
// Layer 1's skip-blend+ELU h tile never leaves the block: after the attn-out MFMAs,
// h (bf16, bit-identical to the store/reload path) is written into the As LDS tile
// (dead after a barrier), Bs is restaged with Wtout, and 8 more MFMAs produce the
// fp32 output projection. Saves 30.7MB h-write + 30.7MB h-read + one full launch.
// h is NOT written to global (no consumer after out-proj).
__global__ __launch_bounds__(256) void mfma_fused_out_k(
    const unsigned short* __restrict__ A0, const unsigned short* __restrict__ Wt0,
    const float* __restrict__ bias0, const unsigned short* __restrict__ H0,
    const float* __restrict__ skip0, const unsigned short* __restrict__ Wo0,
    const float* __restrict__ bo0, float* __restrict__ O0, int N0,
    const unsigned short* __restrict__ A1, const unsigned short* __restrict__ Wt1,
    const float* __restrict__ bias1, const unsigned short* __restrict__ H1,
    const float* __restrict__ skip1, const unsigned short* __restrict__ Wo1,
    const float* __restrict__ bo1, float* __restrict__ O1, int N1,
    int nblk0){
    bool s0 = ((int)blockIdx.x < nblk0);
    const unsigned short* A  = s0 ? A0 : A1;
    const unsigned short* Wt = s0 ? Wt0 : Wt1;
    const float* bias = s0 ? bias0 : bias1;
    const unsigned short* H = s0 ? H0 : H1;
    const float* skip = s0 ? skip0 : skip1;
    const unsigned short* Wo = s0 ? Wo0 : Wo1;
    const float* bo = s0 ? bo0 : bo1;
    float* O = s0 ? O0 : O1;
    int N = s0 ? N0 : N1;
    int bx = s0 ? blockIdx.x : (blockIdx.x - nblk0);

    __shared__ unsigned short As[64][136];
    __shared__ unsigned short Bs[128][136];
    int tid = threadIdx.x;
    int rb = bx*64;
    // stage As = agg tile, Bs = Wta
    #pragma unroll
    for (int ph = 0; ph < 4; ++ph){
        int c = ph*256 + tid;
        int r = c >> 4, off = (c & 15)*8;
        uint4 v = make_uint4(0,0,0,0);
        if (rb + r < N) v = ((const uint4*)(A + (size_t)(rb + r)*128))[c & 15];
        *(uint4*)(&As[r][off]) = v;
    }
    #pragma unroll
    for (int ph = 0; ph < 8; ++ph){
        int c = ph*256 + tid;
        int r = c >> 4, off = (c & 15)*8;
        uint4 v = ((const uint4*)(Wt + (size_t)r*128))[c & 15];
        *(uint4*)(&Bs[r][off]) = v;
    }
    __syncthreads();
    int w = tid >> 6, lane = tid & 63;
    int wr = (w >> 1)*32, wc = (w & 1)*64;
    int m = lane & 31, quad = lane >> 5;
    const unsigned short* ap  = &As[wr + m][quad*8];
    const unsigned short* bp0 = &Bs[wc + m][quad*8];
    const unsigned short* bp1 = &Bs[wc + 32 + m][quad*8];
    float bm = 1.f/(1.f + __expf(-skip[0]));

    facc acc0, acc1;
    #pragma unroll
    for (int i = 0; i < 16; ++i){ acc0[i] = 0.f; acc1[i] = 0.f; }
    #pragma unroll
    for (int kc = 0; kc < 8; ++kc){
        bfrag a  = *(const bfrag*)(ap  + kc*16);
        bfrag b0 = *(const bfrag*)(bp0 + kc*16);
        bfrag b1 = *(const bfrag*)(bp1 + kc*16);
        acc0 = __builtin_amdgcn_mfma_f32_32x32x16_bf16(a, b0, acc0, 0, 0, 0);
        acc1 = __builtin_amdgcn_mfma_f32_32x32x16_bf16(a, b1, acc1, 0, 0, 0);
    }
    __syncthreads();   // all waves done reading As/Bs -> both tiles reusable

    // restage Bs = Wtout (overlaps with epilogue VALU below)
    #pragma unroll
    for (int ph = 0; ph < 8; ++ph){
        int c = ph*256 + tid;
        int r = c >> 4, off = (c & 15)*8;
        uint4 v = ((const uint4*)(Wo + (size_t)r*128))[c & 15];
        *(uint4*)(&Bs[r][off]) = v;
    }
    // epilogue: h = ELU(blend) -> As as bf16 (bit-identical to store/reload path)
    int col0 = wc + m, col1 = col0 + 32;
    float bias0v = bias[col0], bias1v = bias[col1];
    #pragma unroll
    for (int r = 0; r < 16; ++r){
        int lrow = wr + 4*quad + (r & 3) + 8*(r >> 2);
        int grow = rb + lrow;
        if (grow >= N) continue;
        float o0 = acc0[r] + bias0v;
        float o1 = acc1[r] + bias1v;
        size_t i0 = (size_t)grow*128 + col0, i1 = (size_t)grow*128 + col1;
        float v0 = bm*o0 + (1.f - bm)*bu2f(H[i0]);
        float v1 = bm*o1 + (1.f - bm)*bu2f(H[i1]);
        v0 = (v0 > 0.f) ? v0 : expm1f(v0);
        v1 = (v1 > 0.f) ? v1 : expm1f(v1);
        As[lrow][col0] = f2bu(v0);
        As[lrow][col1] = f2bu(v1);
    }
    __syncthreads();

    // output projection: out = h @ Wtout + b_out (fp32)
    facc oc0, oc1;
    #pragma unroll
    for (int i = 0; i < 16; ++i){ oc0[i] = 0.f; oc1[i] = 0.f; }
    #pragma unroll
    for (int kc = 0; kc < 8; ++kc){
        bfrag a  = *(const bfrag*)(ap  + kc*16);
        bfrag b0 = *(const bfrag*)(bp0 + kc*16);
        bfrag b1 = *(const bfrag*)(bp1 + kc*16);
        oc0 = __builtin_amdgcn_mfma_f32_32x32x16_bf16(a, b0, oc0, 0, 0, 0);
        oc1 = __builtin_amdgcn_mfma_f32_32x32x16_bf16(a, b1, oc1, 0, 0, 0);
    }
    float bo0v = bo[col0], bo1v = bo[col1];
    #pragma unroll
    for (int r = 0; r < 16; ++r){
        int lrow = wr + 4*quad + (r & 3) + 8*(r >> 2);
        int grow = rb + lrow;
        if (grow >= N) continue;
        O[(size_t)grow*128 + col0] = oc0[r] + bo0v;
        O[(size_t)grow*128 + col1] = oc1[r] + bo1v;
    }
}

// ---------------- edge attention v7: split q/kv layout ------------------------------
// q row = 128 bf16 (256B); kv row = 256 bf16 (512B contiguous: kt [0:256)B, vt [256:512)B).
// Measured 76.5-77.2us vs 79.0 (768B-stride layout) -- keep. FETCH unchanged
// (224.8MB): the win was address-arithmetic simplicity, not traffic.
// Lane (slot=lane>>4, j=lane&15): 8 dims (uint4 j) of slot's edge; head = j>>2.
// 2-deep pipeline (csr 2 ahead, K/V 1 ahead) -- measured optimum (R2: 3-deep regressed).
__global__ __launch_bounds__(256) void edge_attn7_k(
    const int* __restrict__ ipA, const int* __restrict__ csrA,
    const unsigned short* __restrict__ qdA, const unsigned short* __restrict__ kvA,
    const float* __restrict__ pA, unsigned* __restrict__ aggA, int NdA,
    const int* __restrict__ ipB, const int* __restrict__ csrB,
    const unsigned short* __restrict__ qdB, const unsigned short* __restrict__ kvB,
    const float* __restrict__ pB, unsigned* __restrict__ aggB, int NdB,
    int nblkA){
    bool sA = ((int)blockIdx.x < nblkA);
    const int* ip  = sA ? ipA : ipB;
    const int* csr = sA ? csrA : csrB;
    const uint4* qd = (const uint4*)(sA ? qdA : qdB);
    const char* kvc = (const char*)(sA ? kvA : kvB);
    const float* p = sA ? pA : pB;
    unsigned* agg = sA ? aggA : aggB;
    int Nd = sA ? NdA : NdB;
    int bx = sA ? blockIdx.x : (blockIdx.x - nblkA);
    int wid  = (bx << 2) | (threadIdx.x >> 6);
    int lane = threadIdx.x & 63;
    if (wid >= Nd) return;
    int slot = lane >> 4, j = lane & 15;
    // fold log2(e) into the per-head scale: exp(x) == exp2(x*log2e) -> bare v_exp_f32
    float phL = p[j >> 2] * (SCALE_F * 1.4426950408889634f);
    uint4 qv = qd[(size_t)wid*16 + j];
    f32x2 q2[4];
    q2[0] = (f32x2){lo16(qv.x), hi16(qv.x)};
    q2[1] = (f32x2){lo16(qv.y), hi16(qv.y)};
    q2[2] = (f32x2){lo16(qv.z), hi16(qv.z)};
    q2[3] = (f32x2){lo16(qv.w), hi16(qv.w)};
    int beg = ip[wid], end = ip[wid + 1];
    float den = 0.f;
    f32x2 acc2[4] = {};
    int loff = j*16;
    int i0 = beg + slot;
    if (i0 < end){
        int s0c = csr[i0];
        int i1 = i0 + 4;
        bool m1 = (i1 < end);
        int s1 = m1 ? csr[i1] : 0;          // csr one ahead, ready before loop
        const char* b0 = kvc + (size_t)s0c*512 + loff;
        uint4 kv = *(const uint4*)(b0);
        uint4 vv = *(const uint4*)(b0 + 256);
        while (true){
            // csr TWO ahead; K/V ONE ahead with address already in registers
            int i2 = i1 + 4;
            bool m2 = (i2 < end);
            int s2 = m2 ? csr[i2] : 0;
            uint4 kv2, vv2;
            if (m1){
                const char* b1 = kvc + (size_t)s1*512 + loff;
                kv2 = *(const uint4*)(b1);
                vv2 = *(const uint4*)(b1 + 256);
            }
            f32x2 pp = q2[0] * (f32x2){lo16(kv.x), hi16(kv.x)};
            pp += q2[1] * (f32x2){lo16(kv.y), hi16(kv.y)};
            pp += q2[2] * (f32x2){lo16(kv.z), hi16(kv.z)};
            pp += q2[3] * (f32x2){lo16(kv.w), hi16(kv.w)};
            float part = pp.x + pp.y;
            part += __shfl_xor(part, 1);   // reduce within 4-lane head group
            part += __shfl_xor(part, 2);
            float e = __ocml_native_exp2_f32(part * phL);
            den += e;
            acc2[0] += (f32x2){lo16(vv.x), hi16(vv.x)} * e;
            acc2[1] += (f32x2){lo16(vv.y), hi16(vv.y)} * e;
            acc2[2] += (f32x2){lo16(vv.z), hi16(vv.z)} * e;
            acc2[3] += (f32x2){lo16(vv.w), hi16(vv.w)} * e;
            if (!m1) break;
            kv = kv2; vv = vv2;
            i1 = i2; m1 = m2; s1 = s2;
        }
    }
    // cross-slot reduce (slots hold disjoint edge subsets)
    den += __shfl_xor(den, 16);
    den += __shfl_xor(den, 32);
    #pragma unroll
    for (int k = 0; k < 4; ++k){
        f32x2 t;
        t.x = __shfl_xor(acc2[k].x, 16);
        t.y = __shfl_xor(acc2[k].y, 16);
        acc2[k] += t;
        t.x = __shfl_xor(acc2[k].x, 32);
        t.y = __shfl_xor(acc2[k].y, 32);
        acc2[k] += t;
    }
    float inv = (den > 0.f) ? 1.f/den : 0.f;
    // epilogue: each lane handles dims {8j + 2*slot, 8j + 2*slot + 1} = acc2[slot]
    f32x2 sel = (slot & 2) ? ((slot & 1) ? acc2[3] : acc2[2])
                           : ((slot & 1) ? acc2[1] : acc2[0]);
    float o0 = sel.x*inv, o1 = sel.y*inv;
    o0 = 0.5f*o0*(1.f + erff(o0*0.70710678118654752f));
    o1 = 0.5f*o1*(1.f + erff(o1*0.70710678118654752f));
    agg[(size_t)wid*64 + j*4 + slot] = (unsigned)f2bu(o0) | ((unsigned)f2bu(o1) << 16);
}

// ---------------- host launcher ----------------
extern "C" void kernel_launch(void* const* d_in, const int* in_sizes, int n_in,
                              void* d_out, int out_size, void* d_ws, size_t ws_size,
                              hipStream_t stream){
    typedef const float* FP;
    FP x_m = (FP)d_in[0], x_g = (FP)d_in[1];
    FP W_in_m = (FP)d_in[2], b_in_m = (FP)d_in[3], W_in_g = (FP)d_in[4], b_in_g = (FP)d_in[5];
    FP Wk_m = (FP)d_in[6],  bk_m = (FP)d_in[7],  Wq_m = (FP)d_in[8],  bq_m = (FP)d_in[9];
    FP Wv_m = (FP)d_in[10], bv_m = (FP)d_in[11];
    FP Wk_g = (FP)d_in[12], bk_g = (FP)d_in[13], Wq_g = (FP)d_in[14], bq_g = (FP)d_in[15];
    FP Wv_g = (FP)d_in[16], bv_g = (FP)d_in[17];
    FP a_mg = (FP)d_in[18], m_mg = (FP)d_in[19], p_mg = (FP)d_in[20];
    FP a_gm = (FP)d_in[21], m_gm = (FP)d_in[22], p_gm = (FP)d_in[23];
    FP Wa_m = (FP)d_in[24], ba_m = (FP)d_in[25], Wa_g = (FP)d_in[26], ba_g = (FP)d_in[27];
    FP skip_m = (FP)d_in[28], skip_g = (FP)d_in[29];
    FP W_out_m = (FP)d_in[30], b_out_m = (FP)d_in[31], W_out_g = (FP)d_in[32], b_out_g = (FP)d_in[33];
    const int* e_mg_src = (const int*)d_in[34];
    const int* e_mg_dst = (const int*)d_in[35];
    const int* e_gm_src = (const int*)d_in[36];
    const int* e_gm_dst = (const int*)d_in[37];

    const int Nm = in_sizes[0] / 20;
    const int Ng = in_sizes[1] / 50;
    const int E1 = in_sizes[34];   // m -> g
    const int E2 = in_sizes[36];   // g -> m

    // ---- workspace carve (256B aligned) ----
    char* wp = (char*)d_ws;
    auto alloc = [&](size_t bytes) -> char* {
        char* r = wp; wp += (bytes + 255) & ~(size_t)255; return r;
    };
    unsigned short* h_m   = (unsigned short*)alloc((size_t)Nm*128*2);
    unsigned short* h_g   = (unsigned short*)alloc((size_t)Ng*128*2);
    unsigned short* agg_m = (unsigned short*)alloc((size_t)Nm*128*2);
    unsigned short* agg_g = (unsigned short*)alloc((size_t)Ng*128*2);
    unsigned short* q_m   = (unsigned short*)alloc((size_t)Nm*128*2);
    unsigned short* kv_m  = (unsigned short*)alloc((size_t)Nm*256*2);
    unsigned short* q_g   = (unsigned short*)alloc((size_t)Ng*128*2);
    unsigned short* kv_g  = (unsigned short*)alloc((size_t)Ng*256*2);
    unsigned short* Wtf   = (unsigned short*)alloc((size_t)4*49152*2);  // [l*2+side][384][128]
    float*          bfv   = (float*)alloc((size_t)4*384*4);
    unsigned short* Wta   = (unsigned short*)alloc((size_t)4*16384*2);  // [l*2+side]
    unsigned short* Wtout = (unsigned short*)alloc((size_t)2*16384*2);
    int* indptr_g = (int*)alloc((size_t)(Ng+1)*4);
    int* csr_mg   = (int*)alloc((size_t)E1*4);
    int* indptr_m = (int*)alloc((size_t)(Nm+1)*4);
    int* csr_gm   = (int*)alloc((size_t)E2*4);
    int maxN = Nm > Ng ? Nm : Ng;
    int* cnt  = (int*)alloc((size_t)maxN*4);
    int* cur  = (int*)alloc((size_t)maxN*4);
    int* cnt2 = (int*)alloc((size_t)maxN*4);
    int* cur2 = (int*)alloc((size_t)maxN*4);
    int* incl = (int*)alloc((size_t)maxN*4);
    int* incl2= (int*)alloc((size_t)maxN*4);
    int* bsum = (int*)alloc(512*4);
    int* bsum2= (int*)alloc(512*4);

    size_t used = (size_t)(wp - (char*)d_ws);
    if (used > ws_size){
        hipMemsetAsync(d_out, 0, (size_t)out_size*4, stream);
        return;
    }
    // zero only the atomic counters (everything else write-before-read)
    hipMemsetAsync(cnt, 0, (size_t)((char*)cur2 - (char*)cnt) + (size_t)maxN*4, stream);

    // ---- CSR build, both directions per launch ----
    int maxE = E1 > E2 ? E1 : E2;
    int nb1 = (Ng + 255)/256, nb2 = (Nm + 255)/256;
    int nbmax = nb1 > nb2 ? nb1 : nb2;
    hist2_k<<<dim3((maxE + 255)/256, 2), 256, 0, stream>>>(
        e_mg_dst, cnt, E1, Ng, e_gm_dst, cnt2, E2, Nm);
    scan_block2_k<<<dim3(nbmax, 2), 256, 0, stream>>>(
        cnt, incl, bsum, Ng, cnt2, incl2, bsum2, Nm);
    scan_top2_k<<<2, 512, 0, stream>>>(bsum, nb1, bsum2, nb2);
    finalize2_k<<<dim3(nbmax + 1, 2), 256, 0, stream>>>(
        incl, cnt, bsum, indptr_g, Ng, E1, incl2, cnt2, bsum2, indptr_m, Nm, E2);
    scatter2_k<<<dim3((maxE + 255)/256, 2), 256, 0, stream>>>(
        e_mg_src, e_mg_dst, indptr_g, cur, csr_mg, E1, Ng,
        e_gm_src, e_gm_dst, indptr_m, cur2, csr_gm, E2, Nm);

    // ---- unified weight prep (transposes + fused QKV weights), one launch ----
    wprep_k<<<2304, 128, 0, stream>>>(
        Wq_m, bq_m, Wk_m, bk_m, Wv_m, bv_m, a_mg, m_mg,
        Wq_g, bq_g, Wk_g, bk_g, Wv_g, bv_g, a_gm, m_gm,
        Wtf, bfv, Wa_m, Wa_g, W_out_m, W_out_g, Wta, Wtout);

    // ---- input projections (both sides, one launch) ----
    in_proj2_k<<<dim3(2048, 2), 128, 0, stream>>>(
        x_m, W_in_m, b_in_m, h_m, Nm,
        x_g, W_in_g, b_in_g, h_g, Ng);

    int gxm = (Nm + 63)/64, gxg = (Ng + 63)/64;
    int nbA = (Ng + 3)/4, nbB = (Nm + 3)/4;

    float* outp = (float*)d_out;

    // ---- layer 0 ----
    mfma_gemm2<__hip_bfloat16, 1, 3><<<dim3(gxm + gxg, 1), 256, 0, stream>>>(
        h_m, Wtf + (size_t)0*49152, bfv + 0*384,
        (__hip_bfloat16*)q_m, kv_m, Nm, nullptr,
        h_g, Wtf + (size_t)1*49152, bfv + 1*384,
        (__hip_bfloat16*)q_g, kv_g, Ng, nullptr,
        0, gxm);

    edge_attn7_k<<<nbA + nbB, 256, 0, stream>>>(
        indptr_g, csr_mg, q_g, kv_m, p_mg + 0, (unsigned*)agg_g, Ng,
        indptr_m, csr_gm, q_m, kv_g, p_gm + 0, (unsigned*)agg_m, Nm,
        nbA);

    mfma_gemm2<float, 2, 1><<<dim3(gxm + gxg, 1), 256, 0, stream>>>(
        agg_m, Wta + (size_t)0*16384, ba_m + 0, (float*)nullptr, h_m, Nm, skip_m + 0,
        agg_g, Wta + (size_t)1*16384, ba_g + 0, (float*)nullptr, h_g, Ng, skip_g + 0,
        128, gxm);

    // ---- layer 1 ----
    mfma_gemm2<__hip_bfloat16, 1, 3><<<dim3(gxm + gxg, 1), 256, 0, stream>>>(
        h_m, Wtf + (size_t)2*49152, bfv + 2*384,
        (__hip_bfloat16*)q_m, kv_m, Nm, nullptr,
        h_g, Wtf + (size_t)3*49152, bfv + 3*384,
        (__hip_bfloat16*)q_g, kv_g, Ng, nullptr,
        0, gxm);

    edge_attn7_k<<<nbA + nbB, 256, 0, stream>>>(
        indptr_g, csr_mg, q_g, kv_m, p_mg + 4, (unsigned*)agg_g, Ng,
        indptr_m, csr_gm, q_m, kv_g, p_gm + 4, (unsigned*)agg_m, Nm,
        nbA);

    // fused: layer-1 attn-out (skip-blend+ELU) + output projection, h stays on-chip
    mfma_fused_out_k<<<dim3(gxm + gxg, 1), 256, 0, stream>>>(
        agg_m, Wta + (size_t)2*16384, ba_m + 128, h_m, skip_m + 1,
        Wtout, b_out_m, outp, Nm,
        agg_g, Wta + (size_t)3*16384, ba_g + 128, h_g, skip_g + 1,
        Wtout + 16384, b_out_g, outp + (size_t)Nm*128, Ng,
        gxm);
}

// Round 10
// 573.717 us; speedup vs baseline: 1.1347x; 1.0178x over previous
//
#include <hip/hip_runtime.h>
#include <hip/hip_bf16.h>

#define SCALE_F 0.17677669529663688f  // 1/sqrt(32)

typedef __attribute__((ext_vector_type(8)))  short bfrag;   // 8 bf16 = 4 VGPRs
typedef __attribute__((ext_vector_type(16))) float facc;    // 32x32 C/D: 16 fp32
typedef __attribute__((ext_vector_type(2)))  float f32x2;   // packs to v_pk_* on CDNA

extern "C" __device__ float __ocml_native_exp2_f32(float);  // bare v_exp_f32

__device__ __forceinline__ float lo16(unsigned u){ return __uint_as_float(u << 16); }
__device__ __forceinline__ float hi16(unsigned u){ return __uint_as_float(u & 0xffff0000u); }
__device__ __forceinline__ float bu2f(unsigned short u){ return __uint_as_float((unsigned)u << 16); }
__device__ __forceinline__ unsigned short f2bu(float f){
    __hip_bfloat16 h = __float2bfloat16(f);
    return *reinterpret_cast<unsigned short*>(&h);
}
__device__ __forceinline__ void storeC(float* p, float v){ *p = v; }
__device__ __forceinline__ void storeC(__hip_bfloat16* p, float v){ *p = __float2bfloat16(v); }

// ---------------- CSR build (dual-side kernels: blockIdx.y / blockIdx.x selects side) --
__global__ void hist2_k(const int* __restrict__ d1, int* __restrict__ c1, int E1, int N1,
                        const int* __restrict__ d2, int* __restrict__ c2, int E2, int N2){
    const int* d = blockIdx.y ? d2 : d1;
    int* c = blockIdx.y ? c2 : c1;
    int E = blockIdx.y ? E2 : E1;
    int Nd = blockIdx.y ? N2 : N1;
    int e = blockIdx.x*256 + threadIdx.x;
    if (e >= E) return;
    int dd = d[e];
    if ((unsigned)dd < (unsigned)Nd) atomicAdd(&c[dd], 1);
}

__global__ void scan_block2_k(const int* __restrict__ c1, int* __restrict__ i1, int* __restrict__ b1, int N1,
                              const int* __restrict__ c2, int* __restrict__ i2, int* __restrict__ b2, int N2){
    const int* cnt = blockIdx.y ? c2 : c1;
    int* incl = blockIdx.y ? i2 : i1;
    int* bsum = blockIdx.y ? b2 : b1;
    int N = blockIdx.y ? N2 : N1;
    if ((int)blockIdx.x*256 >= N) return;
    __shared__ int sh[256];
    int tid = threadIdx.x;
    int i = blockIdx.x*256 + tid;
    int v = (i < N) ? cnt[i] : 0;
    sh[tid] = v;
    __syncthreads();
    for (int off = 1; off < 256; off <<= 1){
        int t = (tid >= off) ? sh[tid-off] : 0;
        __syncthreads();
        sh[tid] += t;
        __syncthreads();
    }
    if (i < N) incl[i] = sh[tid];
    if (tid == 255) bsum[blockIdx.x] = sh[255];
}

__global__ void scan_top2_k(int* __restrict__ b1, int nb1, int* __restrict__ b2, int nb2){
    int* bsum = blockIdx.x ? b2 : b1;
    int nb = blockIdx.x ? nb2 : nb1;
    __shared__ int sh[512];
    int tid = threadIdx.x;
    int v = (tid < nb) ? bsum[tid] : 0;
    sh[tid] = v;
    __syncthreads();
    for (int off = 1; off < 512; off <<= 1){
        int t = (tid >= off) ? sh[tid-off] : 0;
        __syncthreads();
        sh[tid] += t;
        __syncthreads();
    }
    if (tid < nb) bsum[tid] = sh[tid] - v;  // exclusive
}

__global__ void finalize2_k(const int* __restrict__ i1, const int* __restrict__ c1,
                            const int* __restrict__ b1, int* __restrict__ p1, int N1, int E1,
                            const int* __restrict__ i2, const int* __restrict__ c2,
                            const int* __restrict__ b2, int* __restrict__ p2, int N2, int E2){
    const int* incl = blockIdx.y ? i2 : i1;
    const int* cnt  = blockIdx.y ? c2 : c1;
    const int* boff = blockIdx.y ? b2 : b1;
    int* indptr = blockIdx.y ? p2 : p1;
    int N = blockIdx.y ? N2 : N1;
    int E = blockIdx.y ? E2 : E1;
    int i = blockIdx.x*256 + threadIdx.x;
    if (i > N) return;
    if (i == N){ indptr[N] = E; return; }
    indptr[i] = boff[i >> 8] + incl[i] - cnt[i];
}

__global__ void scatter2_k(const int* __restrict__ s1, const int* __restrict__ d1,
                           const int* __restrict__ p1, int* __restrict__ u1,
                           int* __restrict__ r1, int E1, int N1,
                           const int* __restrict__ s2, const int* __restrict__ d2,
                           const int* __restrict__ p2, int* __restrict__ u2,
                           int* __restrict__ r2, int E2, int N2){
    const int* src = blockIdx.y ? s2 : s1;
    const int* dst = blockIdx.y ? d2 : d1;
    const int* indptr = blockIdx.y ? p2 : p1;
    int* cur = blockIdx.y ? u2 : u1;
    int* csr = blockIdx.y ? r2 : r1;
    int E = blockIdx.y ? E2 : E1;
    int Nd = blockIdx.y ? N2 : N1;
    int e = blockIdx.x*256 + threadIdx.x;
    if (e >= E) return;
    int d = dst[e];
    if ((unsigned)d >= (unsigned)Nd) return;
    int p = indptr[d] + atomicAdd(&cur[d], 1);
    csr[p] = src[e];
}

// ---------------- input projection: weight-stationary, LDS x-broadcast --------------
template<int K>
__device__ __forceinline__ void in_proj_body(const float* __restrict__ x,
                                             const float* __restrict__ W,
                                             const float* __restrict__ b,
                                             unsigned short* __restrict__ h, int N){
    constexpr int KP4 = (K + 3)/4, KP = KP4*4;
    int j = threadIdx.x;
    float wreg[KP];
    #pragma unroll
    for (int k = 0; k < KP; ++k) wreg[k] = (k < K) ? W[k*128 + j] : 0.f;
    float bj = b[j];
    __shared__ float xs[8][KP];
    for (int base = blockIdx.x*8; base < N; base += gridDim.x*8){
        __syncthreads();
        for (int t = threadIdx.x; t < 8*KP; t += 128){
            int r = t / KP, k = t - r*KP;
            int row = base + r;
            xs[r][k] = (row < N && k < K) ? x[(size_t)row*K + k] : 0.f;
        }
        __syncthreads();
        #pragma unroll
        for (int r = 0; r < 8; ++r){
            int row = base + r;
            if (row >= N) break;
            float acc = bj;
            #pragma unroll
            for (int kk = 0; kk < KP4; ++kk){
                float4 xv = *(const float4*)(&xs[r][kk*4]);
                acc += xv.x*wreg[kk*4] + xv.y*wreg[kk*4+1]
                     + xv.z*wreg[kk*4+2] + xv.w*wreg[kk*4+3];
            }
            h[(size_t)row*128 + j] = f2bu(acc);
        }
    }
}

__global__ __launch_bounds__(128) void in_proj2_k(
    const float* __restrict__ xm, const float* __restrict__ Wm,
    const float* __restrict__ bm_, unsigned short* __restrict__ hm, int Nm,
    const float* __restrict__ xg, const float* __restrict__ Wg,
    const float* __restrict__ bg_, unsigned short* __restrict__ hg, int Ng){
    if (blockIdx.y == 0) in_proj_body<20>(xm, Wm, bm_, hm, Nm);
    else                 in_proj_body<50>(xg, Wg, bg_, hg, Ng);
}

// ---------------- unified weight prep: QKV-fused weights (both layers, both sides)
// + 6-way 128x128 transposes, one launch ---------------------------------------------
__global__ __launch_bounds__(128) void wprep_k(
    const float* __restrict__ Wq_m, const float* __restrict__ bq_m,
    const float* __restrict__ Wk_m, const float* __restrict__ bk_m,
    const float* __restrict__ Wv_m, const float* __restrict__ bv_m,
    const float* __restrict__ a_mg, const float* __restrict__ m_mg,
    const float* __restrict__ Wq_g, const float* __restrict__ bq_g,
    const float* __restrict__ Wk_g, const float* __restrict__ bk_g,
    const float* __restrict__ Wv_g, const float* __restrict__ bv_g,
    const float* __restrict__ a_gm, const float* __restrict__ m_gm,
    unsigned short* __restrict__ Wtf, float* __restrict__ bfv,
    const float* __restrict__ Wa_m, const float* __restrict__ Wa_g,
    const float* __restrict__ W_out_m, const float* __restrict__ W_out_g,
    unsigned short* __restrict__ Wta, unsigned short* __restrict__ Wtout){
    int b = blockIdx.x;
    if (b < 1536){
        int u = b / 384, j = b % 384;
        int l = u >> 1;  bool sg = (u & 1);
        const float* Wq = (sg ? Wq_g : Wq_m) + l*16384;
        const float* bq = (sg ? bq_g : bq_m) + l*128;
        const float* Wk = (sg ? Wk_g : Wk_m) + l*16384;
        const float* bk = (sg ? bk_g : bk_m) + l*128;
        const float* Wv = (sg ? Wv_g : Wv_m) + l*16384;
        const float* bv = (sg ? bv_g : bv_m) + l*128;
        const float* ar = (sg ? a_gm : a_mg) + l*4096;
        const float* mr = (sg ? m_gm : m_mg) + l*4096;
        unsigned short* Wt = Wtf + (size_t)u*49152;
        float* bf = bfv + u*384;
        int row = threadIdx.x;
        int part = j >> 7, f = j & 127, hh = f >> 5, ff = f & 31;
        float v;
        if (part == 0) v = Wq[row*128 + f];
        else {
            const float* Wx  = (part == 1) ? Wk : Wv;
            const float* rel = (part == 1) ? ar : mr;
            float s = 0.f;
            #pragma unroll
            for (int d = 0; d < 32; ++d)
                s += Wx[row*128 + hh*32 + d] * rel[hh*1024 + d*32 + ff];
            v = s;
        }
        Wt[(size_t)j*128 + row] = f2bu(v);
        if (row == 0){
            float bb;
            if (part == 0) bb = bq[f];
            else {
                const float* bx  = (part == 1) ? bk : bv;
                const float* rel = (part == 1) ? ar : mr;
                float s = 0.f;
                for (int d = 0; d < 32; ++d)
                    s += bx[hh*32 + d] * rel[hh*1024 + d*32 + ff];
                bb = s;
            }
            bf[j] = bb;
        }
    } else {
        int t = b - 1536;
        int y = t >> 7;
        int idx = (t & 127)*128 + threadIdx.x;
        const float* S = (y==0)?Wa_m:(y==1)?Wa_g:(y==2)?(Wa_m+16384):(y==3)?(Wa_g+16384)
                        :(y==4)?W_out_m:W_out_g;
        unsigned short* D = (y==0)?Wta:(y==1)?(Wta+16384):(y==2)?(Wta+32768):(y==3)?(Wta+49152)
                           :(y==4)?Wtout:(Wtout+16384);
        int n = idx >> 7, k = idx & 127;
        D[idx] = f2bu(S[k*128 + n]);
    }
}

// ---------------- MFMA GEMM, two independent sides in one launch ---------------------
// C/D: col=lane&31, row=(reg&3)+8*(reg>>2)+4*(lane>>5)   [m74/m101 verified]
// FROZEN R4 structure (measured best over 4 experiments): 128-col chunks, 2
// accumulators/wave, LDS 52KB, 16 MFMAs per barrier pair, DIRECT global->LDS staging.
// Failed alternatives (do not retry): B-direct-from-L2 (R3); 64-col chunks (R6);
// register B-prefetch (R7). Compiler's own staging schedule wins -- Common-mistake #5.
// MODE 0: plain store. MODE 1: split-QKV store. MODE 2: skip-blend + ELU RMW on H.
template<typename CT, int MODE, int NCHUNK>
__global__ __launch_bounds__(256) void mfma_gemm2(
    const unsigned short* __restrict__ A0, const unsigned short* __restrict__ Wt0,
    const float* __restrict__ bias0, CT* __restrict__ C0, unsigned short* __restrict__ H0,
    int N0, const float* __restrict__ skip0,
    const unsigned short* __restrict__ A1, const unsigned short* __restrict__ Wt1,
    const float* __restrict__ bias1, CT* __restrict__ C1, unsigned short* __restrict__ H1,
    int N1, const float* __restrict__ skip1,
    int ldc, int nblk0){
    bool s0 = ((int)blockIdx.x < nblk0);
    const unsigned short* A  = s0 ? A0 : A1;
    const unsigned short* Wt = s0 ? Wt0 : Wt1;
    const float* bias = s0 ? bias0 : bias1;
    CT* C = s0 ? C0 : C1;
    unsigned short* H = s0 ? H0 : H1;
    int N = s0 ? N0 : N1;
    const float* skip = s0 ? skip0 : skip1;
    int bx = s0 ? blockIdx.x : (blockIdx.x - nblk0);

    __shared__ unsigned short As[64][136];
    __shared__ unsigned short Bs[128][136];
    int tid = threadIdx.x;
    int rb = bx*64;
    #pragma unroll
    for (int ph = 0; ph < 4; ++ph){
        int c = ph*256 + tid;
        int r = c >> 4, off = (c & 15)*8;
        uint4 v = make_uint4(0,0,0,0);
        if (rb + r < N) v = ((const uint4*)(A + (size_t)(rb + r)*128))[c & 15];
        *(uint4*)(&As[r][off]) = v;
    }
    int w = tid >> 6, lane = tid & 63;
    int wr = (w >> 1)*32, wc = (w & 1)*64;
    int m = lane & 31, quad = lane >> 5;
    const unsigned short* ap  = &As[wr + m][quad*8];
    const unsigned short* bp0 = &Bs[wc + m][quad*8];
    const unsigned short* bp1 = &Bs[wc + 32 + m][quad*8];
    float bm = 0.f;
    if (MODE == 2) bm = 1.f/(1.f + __expf(-skip[0]));

    #pragma unroll
    for (int chunk = 0; chunk < NCHUNK; ++chunk){
        int cb = chunk*128;
        if (chunk > 0) __syncthreads();   // all waves done reading Bs of prev chunk
        #pragma unroll
        for (int ph = 0; ph < 8; ++ph){
            int c = ph*256 + tid;
            int r = c >> 4, off = (c & 15)*8;
            uint4 v = ((const uint4*)(Wt + (size_t)(cb + r)*128))[c & 15];
            *(uint4*)(&Bs[r][off]) = v;
        }
        __syncthreads();                   // covers As on chunk 0 as well
        facc acc0, acc1;
        #pragma unroll
        for (int i = 0; i < 16; ++i){ acc0[i] = 0.f; acc1[i] = 0.f; }
        #pragma unroll
        for (int kc = 0; kc < 8; ++kc){
            bfrag a  = *(const bfrag*)(ap  + kc*16);
            bfrag b0 = *(const bfrag*)(bp0 + kc*16);
            bfrag b1 = *(const bfrag*)(bp1 + kc*16);
            acc0 = __builtin_amdgcn_mfma_f32_32x32x16_bf16(a, b0, acc0, 0, 0, 0);
            acc1 = __builtin_amdgcn_mfma_f32_32x32x16_bf16(a, b1, acc1, 0, 0, 0);
        }
        int col0 = cb + wc + m, col1 = col0 + 32;
        float bias0v = bias[col0], bias1v = bias[col1];
        #pragma unroll
        for (int r = 0; r < 16; ++r){
            int lrow = wr + 4*quad + (r & 3) + 8*(r >> 2);
            int grow = rb + lrow;
            if (grow >= N) continue;
            float o0 = acc0[r] + bias0v;
            float o1 = acc1[r] + bias1v;
            if (MODE == 0){
                storeC(&C[(size_t)grow*ldc + col0], o0);
                storeC(&C[(size_t)grow*ldc + col1], o1);
            } else if (MODE == 1){
                unsigned short* qp = (unsigned short*)C;
                if (col0 < 128){
                    qp[(size_t)grow*128 + col0] = f2bu(o0);
                    qp[(size_t)grow*128 + col1] = f2bu(o1);
                } else {
                    H[(size_t)grow*256 + (col0 - 128)] = f2bu(o0);
                    H[(size_t)grow*256 + (col1 - 128)] = f2bu(o1);
                }
            } else {
                size_t i0 = (size_t)grow*128 + col0, i1 = (size_t)grow*128 + col1;
                float v0 = bm*o0 + (1.f - bm)*bu2f(H[i0]);
                float v1 = bm*o1 + (1.f - bm)*bu2f(H[i1]);
                v0 = (v0 > 0.f) ? v0 : expm1f(v0);
                v1 = (v1 > 0.f) ? v1 : expm1f(v1);
                H[i0] = f2bu(v0);
                H[i1] = f2bu(v1);
            }
        }
    }
}

// ---------------- fused mid: layer-0 attn-out (skip+ELU) + layer-1 QKV ---------------
// The h tile computed by the attn-out MFMAs is written BOTH to global H (layer-1's
// fused_out still reads it for the skip-blend) and into the dead As LDS tile, then
// layer-1's 3-chunk QKV runs in place. Eliminates layer-1 QKV's 31MB h re-read,
// its A-staging phase, and one launch. h bf16 values are bit-identical to the
// store/reload path (same f2bu), so output is bit-identical.
__global__ __launch_bounds__(256) void mfma_fused_mid_k(
    const unsigned short* __restrict__ A0, const unsigned short* __restrict__ Wt0,
    const float* __restrict__ bias0, unsigned short* __restrict__ H0,
    const float* __restrict__ skip0, const unsigned short* __restrict__ Wf0,
    const float* __restrict__ bf0, unsigned short* __restrict__ q0,
    unsigned short* __restrict__ kv0, int N0,
    const unsigned short* __restrict__ A1, const unsigned short* __restrict__ Wt1,
    const float* __restrict__ bias1, unsigned short* __restrict__ H1,
    const float* __restrict__ skip1, const unsigned short* __restrict__ Wf1,
    const float* __restrict__ bf1, unsigned short* __restrict__ q1,
    unsigned short* __restrict__ kv1, int N1,
    int nblk0){
    bool s0 = ((int)blockIdx.x < nblk0);
    const unsigned short* A  = s0 ? A0 : A1;
    const unsigned short* Wt = s0 ? Wt0 : Wt1;
    const float* bias = s0 ? bias0 : bias1;
    unsigned short* H = s0 ? H0 : H1;
    const float* skip = s0 ? skip0 : skip1;
    const unsigned short* Wf = s0 ? Wf0 : Wf1;
    const float* bf = s0 ? bf0 : bf1;
    unsigned short* q = s0 ? q0 : q1;
    unsigned short* kv = s0 ? kv0 : kv1;
    int N = s0 ? N0 : N1;
    int bx = s0 ? blockIdx.x : (blockIdx.x - nblk0);

    __shared__ unsigned short As[64][136];
    __shared__ unsigned short Bs[128][136];
    int tid = threadIdx.x;
    int rb = bx*64;
    // stage As = agg tile, Bs = Wta (layer-0 attn-out weights)
    #pragma unroll
    for (int ph = 0; ph < 4; ++ph){
        int c = ph*256 + tid;
        int r = c >> 4, off = (c & 15)*8;
        uint4 v = make_uint4(0,0,0,0);
        if (rb + r < N) v = ((const uint4*)(A + (size_t)(rb + r)*128))[c & 15];
        *(uint4*)(&As[r][off]) = v;
    }
    #pragma unroll
    for (int ph = 0; ph < 8; ++ph){
        int c = ph*256 + tid;
        int r = c >> 4, off = (c & 15)*8;
        uint4 v = ((const uint4*)(Wt + (size_t)r*128))[c & 15];
        *(uint4*)(&Bs[r][off]) = v;
    }
    __syncthreads();
    int w = tid >> 6, lane = tid & 63;
    int wr = (w >> 1)*32, wc = (w & 1)*64;
    int m = lane & 31, quad = lane >> 5;
    const unsigned short* ap  = &As[wr + m][quad*8];
    const unsigned short* bp0 = &Bs[wc + m][quad*8];
    const unsigned short* bp1 = &Bs[wc + 32 + m][quad*8];
    float bm = 1.f/(1.f + __expf(-skip[0]));

    // attn-out MFMAs
    facc acc0, acc1;
    #pragma unroll
    for (int i = 0; i < 16; ++i){ acc0[i] = 0.f; acc1[i] = 0.f; }
    #pragma unroll
    for (int kc = 0; kc < 8; ++kc){
        bfrag a  = *(const bfrag*)(ap  + kc*16);
        bfrag b0 = *(const bfrag*)(bp0 + kc*16);
        bfrag b1 = *(const bfrag*)(bp1 + kc*16);
        acc0 = __builtin_amdgcn_mfma_f32_32x32x16_bf16(a, b0, acc0, 0, 0, 0);
        acc1 = __builtin_amdgcn_mfma_f32_32x32x16_bf16(a, b1, acc1, 0, 0, 0);
    }
    __syncthreads();   // all waves done reading As/Bs -> both tiles reusable

    // restage Bs = Wf chunk 0 (overlaps with epilogue VALU below)
    #pragma unroll
    for (int ph = 0; ph < 8; ++ph){
        int c = ph*256 + tid;
        int r = c >> 4, off = (c & 15)*8;
        uint4 v = ((const uint4*)(Wf + (size_t)r*128))[c & 15];
        *(uint4*)(&Bs[r][off]) = v;
    }
    // epilogue: h = ELU(blend) -> global H (needed by layer-1 fused_out) + LDS As
    {
        int col0 = wc + m, col1 = col0 + 32;
        float bias0v = bias[col0], bias1v = bias[col1];
        #pragma unroll
        for (int r = 0; r < 16; ++r){
            int lrow = wr + 4*quad + (r & 3) + 8*(r >> 2);
            int grow = rb + lrow;
            if (grow >= N) continue;
            float o0 = acc0[r] + bias0v;
            float o1 = acc1[r] + bias1v;
            size_t i0 = (size_t)grow*128 + col0, i1 = (size_t)grow*128 + col1;
            float v0 = bm*o0 + (1.f - bm)*bu2f(H[i0]);
            float v1 = bm*o1 + (1.f - bm)*bu2f(H[i1]);
            v0 = (v0 > 0.f) ? v0 : expm1f(v0);
            v1 = (v1 > 0.f) ? v1 : expm1f(v1);
            unsigned short h0 = f2bu(v0), h1 = f2bu(v1);
            H[i0] = h0;  H[i1] = h1;
            As[lrow][col0] = h0;
            As[lrow][col1] = h1;
        }
    }
    __syncthreads();

    // layer-1 QKV: 3x 128-col chunks over the in-LDS h tile (MODE-1 split store)
    #pragma unroll
    for (int chunk = 0; chunk < 3; ++chunk){
        if (chunk > 0){
            __syncthreads();   // all waves done reading Bs of prev chunk
            #pragma unroll
            for (int ph = 0; ph < 8; ++ph){
                int c = ph*256 + tid;
                int r = c >> 4, off = (c & 15)*8;
                uint4 v = ((const uint4*)(Wf + (size_t)(chunk*128 + r)*128))[c & 15];
                *(uint4*)(&Bs[r][off]) = v;
            }
            __syncthreads();
        }
        facc qc0, qc1;
        #pragma unroll
        for (int i = 0; i < 16; ++i){ qc0[i] = 0.f; qc1[i] = 0.f; }
        #pragma unroll
        for (int kc = 0; kc < 8; ++kc){
            bfrag a  = *(const bfrag*)(ap  + kc*16);
            bfrag b0 = *(const bfrag*)(bp0 + kc*16);
            bfrag b1 = *(const bfrag*)(bp1 + kc*16);
            qc0 = __builtin_amdgcn_mfma_f32_32x32x16_bf16(a, b0, qc0, 0, 0, 0);
            qc1 = __builtin_amdgcn_mfma_f32_32x32x16_bf16(a, b1, qc1, 0, 0, 0);
        }
        int col0 = chunk*128 + wc + m, col1 = col0 + 32;
        float bf0v = bf[col0], bf1v = bf[col1];
        #pragma unroll
        for (int r = 0; r < 16; ++r){
            int lrow = wr + 4*quad + (r & 3) + 8*(r >> 2);
            int grow = rb + lrow;
            if (grow >= N) continue;
            float o0 = qc0[r] + bf0v;
            float o1 = qc1[r] + bf1v;
            if (col0 < 128){
                q[(size_t)grow*128 + col0] = f2bu(o0);
                q[(size_t)grow*128 + col1] = f2bu(o1);
            } else {
                kv[(size_t)grow*256 + (col0 - 128)] = f2bu(o0);
                kv[(size_t)grow*256 + (col1 - 128)] = f2bu(o1);
            }
        }
    }
}

// ---------------- fused last-layer attn-out + output projection ----------------------
// (verified R9: -6us, bit-identical) h tile stays on-chip; out-proj runs in place.
__global__ __launch_bounds__(256) void mfma_fused_out_k(
    const unsigned short* __restrict__ A0, const unsigned short* __restrict__ Wt0,
    const float* __restrict__ bias0, const unsigned short* __restrict__ H0,
    const float* __restrict__ skip0, const unsigned short* __restrict__ Wo0,
    const float* __restrict__ bo0, float* __restrict__ O0, int N0,
    const unsigned short* __restrict__ A1, const unsigned short* __restrict__ Wt1,
    const float* __restrict__ bias1, const unsigned short* __restrict__ H1,
    const float* __restrict__ skip1, const unsigned short* __restrict__ Wo1,
    const float* __restrict__ bo1, float* __restrict__ O1, int N1,
    int nblk0){
    bool s0 = ((int)blockIdx.x < nblk0);
    const unsigned short* A  = s0 ? A0 : A1;
    const unsigned short* Wt = s0 ? Wt0 : Wt1;
    const float* bias = s0 ? bias0 : bias1;
    const unsigned short* H = s0 ? H0 : H1;
    const float* skip = s0 ? skip0 : skip1;
    const unsigned short* Wo = s0 ? Wo0 : Wo1;
    const float* bo = s0 ? bo0 : bo1;
    float* O = s0 ? O0 : O1;
    int N = s0 ? N0 : N1;
    int bx = s0 ? blockIdx.x : (blockIdx.x - nblk0);

    __shared__ unsigned short As[64][136];
    __shared__ unsigned short Bs[128][136];
    int tid = threadIdx.x;
    int rb = bx*64;
    #pragma unroll
    for (int ph = 0; ph < 4; ++ph){
        int c = ph*256 + tid;
        int r = c >> 4, off = (c & 15)*8;
        uint4 v = make_uint4(0,0,0,0);
        if (rb + r < N) v = ((const uint4*)(A + (size_t)(rb + r)*128))[c & 15];
        *(uint4*)(&As[r][off]) = v;
    }
    #pragma unroll
    for (int ph = 0; ph < 8; ++ph){
        int c = ph*256 + tid;
        int r = c >> 4, off = (c & 15)*8;
        uint4 v = ((const uint4*)(Wt + (size_t)r*128))[c & 15];
        *(uint4*)(&Bs[r][off]) = v;
    }
    __syncthreads();
    int w = tid >> 6, lane = tid & 63;
    int wr = (w >> 1)*32, wc = (w & 1)*64;
    int m = lane & 31, quad = lane >> 5;
    const unsigned short* ap  = &As[wr + m][quad*8];
    const unsigned short* bp0 = &Bs[wc + m][quad*8];
    const unsigned short* bp1 = &Bs[wc + 32 + m][quad*8];
    float bm = 1.f/(1.f + __expf(-skip[0]));

    facc acc0, acc1;
    #pragma unroll
    for (int i = 0; i < 16; ++i){ acc0[i] = 0.f; acc1[i] = 0.f; }
    #pragma unroll
    for (int kc = 0; kc < 8; ++kc){
        bfrag a  = *(const bfrag*)(ap  + kc*16);
        bfrag b0 = *(const bfrag*)(bp0 + kc*16);
        bfrag b1 = *(const bfrag*)(bp1 + kc*16);
        acc0 = __builtin_amdgcn_mfma_f32_32x32x16_bf16(a, b0, acc0, 0, 0, 0);
        acc1 = __builtin_amdgcn_mfma_f32_32x32x16_bf16(a, b1, acc1, 0, 0, 0);
    }
    __syncthreads();   // all waves done reading As/Bs -> both tiles reusable

    // restage Bs = Wtout (overlaps with epilogue VALU below)
    #pragma unroll
    for (int ph = 0; ph < 8; ++ph){
        int c = ph*256 + tid;
        int r = c >> 4, off = (c & 15)*8;
        uint4 v = ((const uint4*)(Wo + (size_t)r*128))[c & 15];
        *(uint4*)(&Bs[r][off]) = v;
    }
    // epilogue: h = ELU(blend) -> As as bf16 (bit-identical to store/reload path)
    int col0 = wc + m, col1 = col0 + 32;
    float bias0v = bias[col0], bias1v = bias[col1];
    #pragma unroll
    for (int r = 0; r < 16; ++r){
        int lrow = wr + 4*quad + (r & 3) + 8*(r >> 2);
        int grow = rb + lrow;
        if (grow >= N) continue;
        float o0 = acc0[r] + bias0v;
        float o1 = acc1[r] + bias1v;
        size_t i0 = (size_t)grow*128 + col0, i1 = (size_t)grow*128 + col1;
        float v0 = bm*o0 + (1.f - bm)*bu2f(H[i0]);
        float v1 = bm*o1 + (1.f - bm)*bu2f(H[i1]);
        v0 = (v0 > 0.f) ? v0 : expm1f(v0);
        v1 = (v1 > 0.f) ? v1 : expm1f(v1);
        As[lrow][col0] = f2bu(v0);
        As[lrow][col1] = f2bu(v1);
    }
    __syncthreads();

    // output projection: out = h @ Wtout + b_out (fp32)
    facc oc0, oc1;
    #pragma unroll
    for (int i = 0; i < 16; ++i){ oc0[i] = 0.f; oc1[i] = 0.f; }
    #pragma unroll
    for (int kc = 0; kc < 8; ++kc){
        bfrag a  = *(const bfrag*)(ap  + kc*16);
        bfrag b0 = *(const bfrag*)(bp0 + kc*16);
        bfrag b1 = *(const bfrag*)(bp1 + kc*16);
        oc0 = __builtin_amdgcn_mfma_f32_32x32x16_bf16(a, b0, oc0, 0, 0, 0);
        oc1 = __builtin_amdgcn_mfma_f32_32x32x16_bf16(a, b1, oc1, 0, 0, 0);
    }
    float bo0v = bo[col0], bo1v = bo[col1];
    #pragma unroll
    for (int r = 0; r < 16; ++r){
        int lrow = wr + 4*quad + (r & 3) + 8*(r >> 2);
        int grow = rb + lrow;
        if (grow >= N) continue;
        O[(size_t)grow*128 + col0] = oc0[r] + bo0v;
        O[(size_t)grow*128 + col1] = oc1[r] + bo1v;
    }
}

// ---------------- edge attention v7: split q/kv layout ------------------------------
// q row = 128 bf16 (256B); kv row = 256 bf16 (512B contiguous: kt [0:256)B, vt [256:512)B).
// Measured 76.3-77.2us; 2-deep pipeline is the measured optimum (R2: 3-deep regressed).
__global__ __launch_bounds__(256) void edge_attn7_k(
    const int* __restrict__ ipA, const int* __restrict__ csrA,
    const unsigned short* __restrict__ qdA, const unsigned short* __restrict__ kvA,
    const float* __restrict__ pA, unsigned* __restrict__ aggA, int NdA,
    const int* __restrict__ ipB, const int* __restrict__ csrB,
    const unsigned short* __restrict__ qdB, const unsigned short* __restrict__ kvB,
    const float* __restrict__ pB, unsigned* __restrict__ aggB, int NdB,
    int nblkA){
    bool sA = ((int)blockIdx.x < nblkA);
    const int* ip  = sA ? ipA : ipB;
    const int* csr = sA ? csrA : csrB;
    const uint4* qd = (const uint4*)(sA ? qdA : qdB);
    const char* kvc = (const char*)(sA ? kvA : kvB);
    const float* p = sA ? pA : pB;
    unsigned* agg = sA ? aggA : aggB;
    int Nd = sA ? NdA : NdB;
    int bx = sA ? blockIdx.x : (blockIdx.x - nblkA);
    int wid  = (bx << 2) | (threadIdx.x >> 6);
    int lane = threadIdx.x & 63;
    if (wid >= Nd) return;
    int slot = lane >> 4, j = lane & 15;
    // fold log2(e) into the per-head scale: exp(x) == exp2(x*log2e) -> bare v_exp_f32
    float phL = p[j >> 2] * (SCALE_F * 1.4426950408889634f);
    uint4 qv = qd[(size_t)wid*16 + j];
    f32x2 q2[4];
    q2[0] = (f32x2){lo16(qv.x), hi16(qv.x)};
    q2[1] = (f32x2){lo16(qv.y), hi16(qv.y)};
    q2[2] = (f32x2){lo16(qv.z), hi16(qv.z)};
    q2[3] = (f32x2){lo16(qv.w), hi16(qv.w)};
    int beg = ip[wid], end = ip[wid + 1];
    float den = 0.f;
    f32x2 acc2[4] = {};
    int loff = j*16;
    int i0 = beg + slot;
    if (i0 < end){
        int s0c = csr[i0];
        int i1 = i0 + 4;
        bool m1 = (i1 < end);
        int s1 = m1 ? csr[i1] : 0;          // csr one ahead, ready before loop
        const char* b0 = kvc + (size_t)s0c*512 + loff;
        uint4 kv = *(const uint4*)(b0);
        uint4 vv = *(const uint4*)(b0 + 256);
        while (true){
            // csr TWO ahead; K/V ONE ahead with address already in registers
            int i2 = i1 + 4;
            bool m2 = (i2 < end);
            int s2 = m2 ? csr[i2] : 0;
            uint4 kv2, vv2;
            if (m1){
                const char* b1 = kvc + (size_t)s1*512 + loff;
                kv2 = *(const uint4*)(b1);
                vv2 = *(const uint4*)(b1 + 256);
            }
            f32x2 pp = q2[0] * (f32x2){lo16(kv.x), hi16(kv.x)};
            pp += q2[1] * (f32x2){lo16(kv.y), hi16(kv.y)};
            pp += q2[2] * (f32x2){lo16(kv.z), hi16(kv.z)};
            pp += q2[3] * (f32x2){lo16(kv.w), hi16(kv.w)};
            float part = pp.x + pp.y;
            part += __shfl_xor(part, 1);   // reduce within 4-lane head group
            part += __shfl_xor(part, 2);
            float e = __ocml_native_exp2_f32(part * phL);
            den += e;
            acc2[0] += (f32x2){lo16(vv.x), hi16(vv.x)} * e;
            acc2[1] += (f32x2){lo16(vv.y), hi16(vv.y)} * e;
            acc2[2] += (f32x2){lo16(vv.z), hi16(vv.z)} * e;
            acc2[3] += (f32x2){lo16(vv.w), hi16(vv.w)} * e;
            if (!m1) break;
            kv = kv2; vv = vv2;
            i1 = i2; m1 = m2; s1 = s2;
        }
    }
    // cross-slot reduce (slots hold disjoint edge subsets)
    den += __shfl_xor(den, 16);
    den += __shfl_xor(den, 32);
    #pragma unroll
    for (int k = 0; k < 4; ++k){
        f32x2 t;
        t.x = __shfl_xor(acc2[k].x, 16);
        t.y = __shfl_xor(acc2[k].y, 16);
        acc2[k] += t;
        t.x = __shfl_xor(acc2[k].x, 32);
        t.y = __shfl_xor(acc2[k].y, 32);
        acc2[k] += t;
    }
    float inv = (den > 0.f) ? 1.f/den : 0.f;
    // epilogue: each lane handles dims {8j + 2*slot, 8j + 2*slot + 1} = acc2[slot]
    f32x2 sel = (slot & 2) ? ((slot & 1) ? acc2[3] : acc2[2])
                           : ((slot & 1) ? acc2[1] : acc2[0]);
    float o0 = sel.x*inv, o1 = sel.y*inv;
    o0 = 0.5f*o0*(1.f + erff(o0*0.70710678118654752f));
    o1 = 0.5f*o1*(1.f + erff(o1*0.70710678118654752f));
    agg[(size_t)wid*64 + j*4 + slot] = (unsigned)f2bu(o0) | ((unsigned)f2bu(o1) << 16);
}

// ---------------- host launcher ----------------
extern "C" void kernel_launch(void* const* d_in, const int* in_sizes, int n_in,
                              void* d_out, int out_size, void* d_ws, size_t ws_size,
                              hipStream_t stream){
    typedef const float* FP;
    FP x_m = (FP)d_in[0], x_g = (FP)d_in[1];
    FP W_in_m = (FP)d_in[2], b_in_m = (FP)d_in[3], W_in_g = (FP)d_in[4], b_in_g = (FP)d_in[5];
    FP Wk_m = (FP)d_in[6],  bk_m = (FP)d_in[7],  Wq_m = (FP)d_in[8],  bq_m = (FP)d_in[9];
    FP Wv_m = (FP)d_in[10], bv_m = (FP)d_in[11];
    FP Wk_g = (FP)d_in[12], bk_g = (FP)d_in[13], Wq_g = (FP)d_in[14], bq_g = (FP)d_in[15];
    FP Wv_g = (FP)d_in[16], bv_g = (FP)d_in[17];
    FP a_mg = (FP)d_in[18], m_mg = (FP)d_in[19], p_mg = (FP)d_in[20];
    FP a_gm = (FP)d_in[21], m_gm = (FP)d_in[22], p_gm = (FP)d_in[23];
    FP Wa_m = (FP)d_in[24], ba_m = (FP)d_in[25], Wa_g = (FP)d_in[26], ba_g = (FP)d_in[27];
    FP skip_m = (FP)d_in[28], skip_g = (FP)d_in[29];
    FP W_out_m = (FP)d_in[30], b_out_m = (FP)d_in[31], W_out_g = (FP)d_in[32], b_out_g = (FP)d_in[33];
    const int* e_mg_src = (const int*)d_in[34];
    const int* e_mg_dst = (const int*)d_in[35];
    const int* e_gm_src = (const int*)d_in[36];
    const int* e_gm_dst = (const int*)d_in[37];

    const int Nm = in_sizes[0] / 20;
    const int Ng = in_sizes[1] / 50;
    const int E1 = in_sizes[34];   // m -> g
    const int E2 = in_sizes[36];   // g -> m

    // ---- workspace carve (256B aligned) ----
    char* wp = (char*)d_ws;
    auto alloc = [&](size_t bytes) -> char* {
        char* r = wp; wp += (bytes + 255) & ~(size_t)255; return r;
    };
    unsigned short* h_m   = (unsigned short*)alloc((size_t)Nm*128*2);
    unsigned short* h_g   = (unsigned short*)alloc((size_t)Ng*128*2);
    unsigned short* agg_m = (unsigned short*)alloc((size_t)Nm*128*2);
    unsigned short* agg_g = (unsigned short*)alloc((size_t)Ng*128*2);
    unsigned short* q_m   = (unsigned short*)alloc((size_t)Nm*128*2);
    unsigned short* kv_m  = (unsigned short*)alloc((size_t)Nm*256*2);
    unsigned short* q_g   = (unsigned short*)alloc((size_t)Ng*128*2);
    unsigned short* kv_g  = (unsigned short*)alloc((size_t)Ng*256*2);
    unsigned short* Wtf   = (unsigned short*)alloc((size_t)4*49152*2);  // [l*2+side][384][128]
    float*          bfv   = (float*)alloc((size_t)4*384*4);
    unsigned short* Wta   = (unsigned short*)alloc((size_t)4*16384*2);  // [l*2+side]
    unsigned short* Wtout = (unsigned short*)alloc((size_t)2*16384*2);
    int* indptr_g = (int*)alloc((size_t)(Ng+1)*4);
    int* csr_mg   = (int*)alloc((size_t)E1*4);
    int* indptr_m = (int*)alloc((size_t)(Nm+1)*4);
    int* csr_gm   = (int*)alloc((size_t)E2*4);
    int maxN = Nm > Ng ? Nm : Ng;
    int* cnt  = (int*)alloc((size_t)maxN*4);
    int* cur  = (int*)alloc((size_t)maxN*4);
    int* cnt2 = (int*)alloc((size_t)maxN*4);
    int* cur2 = (int*)alloc((size_t)maxN*4);
    int* incl = (int*)alloc((size_t)maxN*4);
    int* incl2= (int*)alloc((size_t)maxN*4);
    int* bsum = (int*)alloc(512*4);
    int* bsum2= (int*)alloc(512*4);

    size_t used = (size_t)(wp - (char*)d_ws);
    if (used > ws_size){
        hipMemsetAsync(d_out, 0, (size_t)out_size*4, stream);
        return;
    }
    // zero only the atomic counters (everything else write-before-read)
    hipMemsetAsync(cnt, 0, (size_t)((char*)cur2 - (char*)cnt) + (size_t)maxN*4, stream);

    // ---- CSR build, both directions per launch ----
    int maxE = E1 > E2 ? E1 : E2;
    int nb1 = (Ng + 255)/256, nb2 = (Nm + 255)/256;
    int nbmax = nb1 > nb2 ? nb1 : nb2;
    hist2_k<<<dim3((maxE + 255)/256, 2), 256, 0, stream>>>(
        e_mg_dst, cnt, E1, Ng, e_gm_dst, cnt2, E2, Nm);
    scan_block2_k<<<dim3(nbmax, 2), 256, 0, stream>>>(
        cnt, incl, bsum, Ng, cnt2, incl2, bsum2, Nm);
    scan_top2_k<<<2, 512, 0, stream>>>(bsum, nb1, bsum2, nb2);
    finalize2_k<<<dim3(nbmax + 1, 2), 256, 0, stream>>>(
        incl, cnt, bsum, indptr_g, Ng, E1, incl2, cnt2, bsum2, indptr_m, Nm, E2);
    scatter2_k<<<dim3((maxE + 255)/256, 2), 256, 0, stream>>>(
        e_mg_src, e_mg_dst, indptr_g, cur, csr_mg, E1, Ng,
        e_gm_src, e_gm_dst, indptr_m, cur2, csr_gm, E2, Nm);

    // ---- unified weight prep (transposes + fused QKV weights), one launch ----
    wprep_k<<<2304, 128, 0, stream>>>(
        Wq_m, bq_m, Wk_m, bk_m, Wv_m, bv_m, a_mg, m_mg,
        Wq_g, bq_g, Wk_g, bk_g, Wv_g, bv_g, a_gm, m_gm,
        Wtf, bfv, Wa_m, Wa_g, W_out_m, W_out_g, Wta, Wtout);

    // ---- input projections (both sides, one launch) ----
    in_proj2_k<<<dim3(2048, 2), 128, 0, stream>>>(
        x_m, W_in_m, b_in_m, h_m, Nm,
        x_g, W_in_g, b_in_g, h_g, Ng);

    int gxm = (Nm + 63)/64, gxg = (Ng + 63)/64;
    int nbA = (Ng + 3)/4, nbB = (Nm + 3)/4;

    float* outp = (float*)d_out;

    // ---- layer 0 QKV ----
    mfma_gemm2<__hip_bfloat16, 1, 3><<<dim3(gxm + gxg, 1), 256, 0, stream>>>(
        h_m, Wtf + (size_t)0*49152, bfv + 0*384,
        (__hip_bfloat16*)q_m, kv_m, Nm, nullptr,
        h_g, Wtf + (size_t)1*49152, bfv + 1*384,
        (__hip_bfloat16*)q_g, kv_g, Ng, nullptr,
        0, gxm);

    edge_attn7_k<<<nbA + nbB, 256, 0, stream>>>(
        indptr_g, csr_mg, q_g, kv_m, p_mg + 0, (unsigned*)agg_g, Ng,
        indptr_m, csr_gm, q_m, kv_g, p_gm + 0, (unsigned*)agg_m, Nm,
        nbA);

    // fused: layer-0 attn-out (skip+ELU, h -> global+LDS) + layer-1 QKV in place
    mfma_fused_mid_k<<<dim3(gxm + gxg, 1), 256, 0, stream>>>(
        agg_m, Wta + (size_t)0*16384, ba_m + 0, h_m, skip_m + 0,
        Wtf + (size_t)2*49152, bfv + 2*384, q_m, kv_m, Nm,
        agg_g, Wta + (size_t)1*16384, ba_g + 0, h_g, skip_g + 0,
        Wtf + (size_t)3*49152, bfv + 3*384, q_g, kv_g, Ng,
        gxm);

    edge_attn7_k<<<nbA + nbB, 256, 0, stream>>>(
        indptr_g, csr_mg, q_g, kv_m, p_mg + 4, (unsigned*)agg_g, Ng,
        indptr_m, csr_gm, q_m, kv_g, p_gm + 4, (unsigned*)agg_m, Nm,
        nbA);

    // fused: layer-1 attn-out (skip-blend+ELU) + output projection, h stays on-chip
    mfma_fused_out_k<<<dim3(gxm + gxg, 1), 256, 0, stream>>>(
        agg_m, Wta + (size_t)2*16384, ba_m + 128, h_m, skip_m + 1,
        Wtout, b_out_m, outp, Nm,
        agg_g, Wta + (size_t)3*16384, ba_g + 128, h_g, skip_g + 1,
        Wtout + 16384, b_out_g, outp + (size_t)Nm*128, Ng,
        gxm);
}